// Round 1
// baseline (959.430 us; speedup 1.0000x reference)
//
#include <hip/hip_runtime.h>

#define N_TOT 8192
#define SEQ_L 512
#define D 128
#define BI 32
#define TJ 64

// ---------------- MLP: y = relu(x @ w1^T + b1) @ w2^T + b2 ----------------
__global__ __launch_bounds__(256) void mlp_kernel(
    const float* __restrict__ x,
    const float* __restrict__ w1, const float* __restrict__ b1,
    const float* __restrict__ w2, const float* __restrict__ b2,
    float* __restrict__ y)
{
    __shared__ float xs[8][D];
    __shared__ float hs[8][256];
    const int t = threadIdx.x;
    const int r0 = blockIdx.x * 8;

    // stage 8 input rows (coalesced float4)
    {
        const float4* xv = (const float4*)(x + (size_t)r0 * D);
        float4 v = xv[t];
        int rr = t >> 5, cc = (t & 31) << 2;
        xs[rr][cc + 0] = v.x; xs[rr][cc + 1] = v.y;
        xs[rr][cc + 2] = v.z; xs[rr][cc + 3] = v.w;
    }
    __syncthreads();

    // hidden: thread t owns hidden unit t for all 8 rows
    {
        const float* w1r = w1 + t * D;
        float bb = b1[t];
        float acc[8];
        #pragma unroll
        for (int r = 0; r < 8; ++r) acc[r] = bb;
        for (int d = 0; d < D; ++d) {
            float w = w1r[d];
            #pragma unroll
            for (int r = 0; r < 8; ++r) acc[r] = fmaf(xs[r][d], w, acc[r]);
        }
        #pragma unroll
        for (int r = 0; r < 8; ++r) hs[r][t] = fmaxf(acc[r], 0.f);
    }
    __syncthreads();

    // output: thread t owns col (t&127), rows (t>>7)*4 .. +3
    {
        int col = t & 127;
        int rb = (t >> 7) << 2;
        const float* w2r = w2 + col * 256;
        float bb = b2[col];
        float acc[4] = {bb, bb, bb, bb};
        for (int k = 0; k < 256; ++k) {
            float w = w2r[k];
            #pragma unroll
            for (int r = 0; r < 4; ++r) acc[r] = fmaf(hs[rb + r][k], w, acc[r]);
        }
        #pragma unroll
        for (int r = 0; r < 4; ++r) y[(size_t)(r0 + rb + r) * D + col] = acc[r];
    }
}

// ---------------- BatchNorm stats: one block per column ----------------
__global__ __launch_bounds__(256) void bn_stats_kernel(
    const float* __restrict__ y, const float* __restrict__ gamma,
    float* __restrict__ mu, float* __restrict__ sc)
{
    const int d = blockIdx.x;
    const int t = threadIdx.x;
    float s = 0.f, ss = 0.f;
    for (int r = t; r < N_TOT; r += 256) {
        float v = y[(size_t)r * D + d];
        s += v; ss += v * v;
    }
    __shared__ float rs[256], rss[256];
    rs[t] = s; rss[t] = ss;
    __syncthreads();
    for (int o = 128; o; o >>= 1) {
        if (t < o) { rs[t] += rs[t + o]; rss[t] += rss[t + o]; }
        __syncthreads();
    }
    if (t == 0) {
        float m = rs[0] / (float)N_TOT;
        float var = rss[0] / (float)N_TOT - m * m;
        mu[d] = m;
        sc[d] = gamma[d] * rsqrtf(var + 1e-5f);
    }
}

// ---------------- BN apply + L2 normalize (in place), 1 wave per row ----------------
__global__ __launch_bounds__(256) void bn_l2_kernel(
    float* __restrict__ y, const float* __restrict__ mu, const float* __restrict__ sc,
    const float* __restrict__ beta)
{
    const int t = threadIdx.x;
    const int lane = t & 63;
    const int row = blockIdx.x * 4 + (t >> 6);
    float* yr = y + (size_t)row * D;
    float v0 = (yr[lane]      - mu[lane])      * sc[lane]      + beta[lane];
    float v1 = (yr[lane + 64] - mu[lane + 64]) * sc[lane + 64] + beta[lane + 64];
    float ssq = v0 * v0 + v1 * v1;
    #pragma unroll
    for (int m = 32; m; m >>= 1) ssq += __shfl_xor(ssq, m);
    float rn = rsqrtf(ssq);
    yr[lane]      = v0 * rn;
    yr[lane + 64] = v1 * rn;
}

// ---------------- Fused S-tile + masked logsumexp loss ----------------
__global__ __launch_bounds__(256) void loss_kernel(
    const float* __restrict__ z1, const float* __restrict__ z2,
    const int* __restrict__ ids, float* __restrict__ partials)
{
    __shared__ float z1s[BI][D + 1];
    __shared__ float z2s[TJ][D + 1];
    __shared__ int   idsj[TJ];
    __shared__ float diag_sh[BI], next_sh[BI], denom_sh[BI];

    const int t  = threadIdx.x;
    const int ty = t >> 5;   // 0..7
    const int tx = t & 31;   // 0..31
    const int i0 = blockIdx.x * BI;

    // stage z1 rows (coalesced float4 -> padded LDS)
    {
        const float4* zv = (const float4*)(z1 + (size_t)i0 * D);
        for (int q = t; q < BI * (D / 4); q += 256) {
            float4 v = zv[q];
            int rr = q >> 5, cc = (q & 31) << 2;
            z1s[rr][cc] = v.x; z1s[rr][cc + 1] = v.y;
            z1s[rr][cc + 2] = v.z; z1s[rr][cc + 3] = v.w;
        }
        if (t < BI) { diag_sh[t] = 0.f; next_sh[t] = 0.f; }
    }

    // per-thread row metadata: rows i0 + ty + 8*ri
    int  idi[4], idn[4], seqi4[4];
    bool two4[4];
    #pragma unroll
    for (int ri = 0; ri < 4; ++ri) {
        int i = i0 + ty + 8 * ri;
        idi[ri]   = ids[i];
        idn[ri]   = ids[(i + 1) % N_TOT];
        seqi4[ri] = i / SEQ_L;
        two4[ri]  = ((i % SEQ_L) != (SEQ_L - 1));
    }

    float dpart[4] = {0.f, 0.f, 0.f, 0.f};

    for (int j0 = 0; j0 < N_TOT; j0 += TJ) {
        __syncthreads();
        {
            const float4* zv = (const float4*)(z2 + (size_t)j0 * D);
            for (int q = t; q < TJ * (D / 4); q += 256) {
                float4 v = zv[q];
                int rr = q >> 5, cc = (q & 31) << 2;
                z2s[rr][cc] = v.x; z2s[rr][cc + 1] = v.y;
                z2s[rr][cc + 2] = v.z; z2s[rr][cc + 3] = v.w;
            }
            if (t < TJ) idsj[t] = ids[j0 + t];
        }
        __syncthreads();

        float a00 = 0.f, a01 = 0.f, a10 = 0.f, a11 = 0.f;
        float a20 = 0.f, a21 = 0.f, a30 = 0.f, a31 = 0.f;
        #pragma unroll 4
        for (int k = 0; k < D; ++k) {
            float b0 = z2s[tx][k];
            float b1 = z2s[tx + 32][k];
            float x0 = z1s[ty][k];
            float x1 = z1s[ty + 8][k];
            float x2 = z1s[ty + 16][k];
            float x3 = z1s[ty + 24][k];
            a00 = fmaf(x0, b0, a00); a01 = fmaf(x0, b1, a01);
            a10 = fmaf(x1, b0, a10); a11 = fmaf(x1, b1, a11);
            a20 = fmaf(x2, b0, a20); a21 = fmaf(x2, b1, a21);
            a30 = fmaf(x3, b0, a30); a31 = fmaf(x3, b1, a31);
        }
        float acc[4][2] = {{a00, a01}, {a10, a11}, {a20, a21}, {a30, a31}};

        #pragma unroll
        for (int ri = 0; ri < 4; ++ri) {
            int i = i0 + ty + 8 * ri;
            #pragma unroll
            for (int ci = 0; ci < 2; ++ci) {
                int j = j0 + tx + 32 * ci;
                float s = acc[ri][ci];
                if (j == i) diag_sh[ty + 8 * ri] = s;
                if (two4[ri] && j == i + 1) next_sh[ty + 8 * ri] = s;
                bool m;
                if (j == i || (two4[ri] && j == i + 1)) {
                    m = true;
                } else {
                    int idj = idsj[tx + 32 * ci];
                    bool n1 = (idj != idi[ri]);
                    m = two4[ri] ? (n1 && (idj != idn[ri]) && ((j / SEQ_L) != seqi4[ri]))
                                 : n1;
                }
                if (m) dpart[ri] += __expf(s);
            }
        }
    }

    // reduce denominators across tx (32-lane groups)
    #pragma unroll
    for (int ri = 0; ri < 4; ++ri) {
        float v = dpart[ri];
        v += __shfl_xor(v, 16);
        v += __shfl_xor(v, 8);
        v += __shfl_xor(v, 4);
        v += __shfl_xor(v, 2);
        v += __shfl_xor(v, 1);
        if (tx == 0) denom_sh[ty + 8 * ri] = v;
    }
    __syncthreads();

    if (t < 64) {
        float v = 0.f;
        if (t < BI) {
            int i = i0 + t;
            bool two = ((i % SEQ_L) != (SEQ_L - 1));
            float pos  = diag_sh[t] + (two ? next_sh[t] : 0.f);
            float npos = two ? 2.f : 1.f;
            v = -(pos - logf(denom_sh[t])) / npos;
        }
        #pragma unroll
        for (int m = 32; m; m >>= 1) v += __shfl_xor(v, m);
        if (t == 0) partials[blockIdx.x] = v;
    }
}

__global__ __launch_bounds__(256) void final_reduce_kernel(
    const float* __restrict__ partials, float* __restrict__ out)
{
    const int t = threadIdx.x;
    float v = partials[t];
    #pragma unroll
    for (int m = 32; m; m >>= 1) v += __shfl_xor(v, m);
    __shared__ float wsum[4];
    if ((t & 63) == 0) wsum[t >> 6] = v;
    __syncthreads();
    if (t == 0) out[0] = (wsum[0] + wsum[1] + wsum[2] + wsum[3]) / (float)N_TOT;
}

extern "C" void kernel_launch(void* const* d_in, const int* in_sizes, int n_in,
                              void* d_out, int out_size, void* d_ws, size_t ws_size,
                              hipStream_t stream)
{
    const int*   ids   = (const int*)d_in[0];
    // d_in[1] = log_mask (unused by the reference)
    const float* x1    = (const float*)d_in[2];
    const float* x2    = (const float*)d_in[3];
    const float* w1    = (const float*)d_in[4];
    const float* b1    = (const float*)d_in[5];
    const float* w2    = (const float*)d_in[6];
    const float* b2    = (const float*)d_in[7];
    const float* gamma = (const float*)d_in[8];
    const float* beta  = (const float*)d_in[9];

    float* ws = (float*)d_ws;
    float* z1 = ws;                               // N*D
    float* z2 = z1 + (size_t)N_TOT * D;           // N*D
    float* mu1 = z2 + (size_t)N_TOT * D;          // D
    float* sc1 = mu1 + D;                         // D
    float* mu2 = sc1 + D;                         // D
    float* sc2 = mu2 + D;                         // D
    float* partials = sc2 + D;                    // N_TOT/BI = 256

    mlp_kernel<<<N_TOT / 8, 256, 0, stream>>>(x1, w1, b1, w2, b2, z1);
    mlp_kernel<<<N_TOT / 8, 256, 0, stream>>>(x2, w1, b1, w2, b2, z2);
    bn_stats_kernel<<<D, 256, 0, stream>>>(z1, gamma, mu1, sc1);
    bn_stats_kernel<<<D, 256, 0, stream>>>(z2, gamma, mu2, sc2);
    bn_l2_kernel<<<N_TOT / 4, 256, 0, stream>>>(z1, mu1, sc1, beta);
    bn_l2_kernel<<<N_TOT / 4, 256, 0, stream>>>(z2, mu2, sc2, beta);
    loss_kernel<<<N_TOT / BI, 256, 0, stream>>>(z1, z2, ids, partials);
    final_reduce_kernel<<<1, 256, 0, stream>>>(partials, (float*)d_out);
}

// Round 3
// 219.594 us; speedup vs baseline: 4.3691x; 4.3691x over previous
//
#include <hip/hip_runtime.h>

#define N_TOT 8192
#define SEQ_L 512
#define D 128

using bf16x8 = __attribute__((ext_vector_type(8))) short;
using f32x4  = __attribute__((ext_vector_type(4))) float;

static __device__ __forceinline__ unsigned short f2bf(float f) {
    unsigned int u = __float_as_uint(f);
    u = (u + 0x7FFFu + ((u >> 16) & 1u)) >> 16;
    return (unsigned short)u;
}
static __device__ __forceinline__ float bf2f(unsigned short h) {
    return __uint_as_float(((unsigned int)h) << 16);
}

// ---------------- MLP: y = relu(x @ w1^T + b1) @ w2^T + b2  (bf16 out) ----------------
__global__ __launch_bounds__(256) void mlp_kernel(
    const float* __restrict__ x,
    const float* __restrict__ w1, const float* __restrict__ b1,
    const float* __restrict__ w2, const float* __restrict__ b2,
    unsigned short* __restrict__ y)
{
    __shared__ float xs[8][D];
    __shared__ float hs[8][256];
    const int t = threadIdx.x;
    const int r0 = blockIdx.x * 8;

    {
        const float4* xv = (const float4*)(x + (size_t)r0 * D);
        float4 v = xv[t];
        int rr = t >> 5, cc = (t & 31) << 2;
        xs[rr][cc + 0] = v.x; xs[rr][cc + 1] = v.y;
        xs[rr][cc + 2] = v.z; xs[rr][cc + 3] = v.w;
    }
    __syncthreads();

    {
        const float* w1r = w1 + t * D;
        float bb = b1[t];
        float acc[8];
        #pragma unroll
        for (int r = 0; r < 8; ++r) acc[r] = bb;
        for (int d = 0; d < D; ++d) {
            float w = w1r[d];
            #pragma unroll
            for (int r = 0; r < 8; ++r) acc[r] = fmaf(xs[r][d], w, acc[r]);
        }
        #pragma unroll
        for (int r = 0; r < 8; ++r) hs[r][t] = fmaxf(acc[r], 0.f);
    }
    __syncthreads();

    {
        int col = t & 127;
        int rb = (t >> 7) << 2;
        const float* w2r = w2 + col * 256;
        float bb = b2[col];
        float acc[4] = {bb, bb, bb, bb};
        for (int k = 0; k < 256; ++k) {
            float w = w2r[k];
            #pragma unroll
            for (int r = 0; r < 4; ++r) acc[r] = fmaf(hs[rb + r][k], w, acc[r]);
        }
        #pragma unroll
        for (int r = 0; r < 4; ++r) y[(size_t)(r0 + rb + r) * D + col] = f2bf(acc[r]);
    }
}

// ---------------- BatchNorm stats: one block per column ----------------
__global__ __launch_bounds__(256) void bn_stats_kernel(
    const unsigned short* __restrict__ y, const float* __restrict__ gamma,
    float* __restrict__ mu, float* __restrict__ sc)
{
    const int d = blockIdx.x;
    const int t = threadIdx.x;
    float s = 0.f, ss = 0.f;
    for (int r = t; r < N_TOT; r += 256) {
        float v = bf2f(y[(size_t)r * D + d]);
        s += v; ss += v * v;
    }
    __shared__ float rs[256], rss[256];
    rs[t] = s; rss[t] = ss;
    __syncthreads();
    for (int o = 128; o; o >>= 1) {
        if (t < o) { rs[t] += rs[t + o]; rss[t] += rss[t + o]; }
        __syncthreads();
    }
    if (t == 0) {
        float m = rs[0] / (float)N_TOT;
        float var = rss[0] / (float)N_TOT - m * m;
        mu[d] = m;
        sc[d] = gamma[d] * rsqrtf(var + 1e-5f);
    }
}

// ---------------- BN apply + L2 normalize (bf16 in/out, in place) ----------------
__global__ __launch_bounds__(256) void bn_l2_kernel(
    unsigned short* __restrict__ y, const float* __restrict__ mu,
    const float* __restrict__ sc, const float* __restrict__ beta)
{
    const int t = threadIdx.x;
    const int lane = t & 63;
    const int row = blockIdx.x * 4 + (t >> 6);
    unsigned short* yr = y + (size_t)row * D;
    float v0 = (bf2f(yr[lane])      - mu[lane])      * sc[lane]      + beta[lane];
    float v1 = (bf2f(yr[lane + 64]) - mu[lane + 64]) * sc[lane + 64] + beta[lane + 64];
    float ssq = v0 * v0 + v1 * v1;
    #pragma unroll
    for (int m = 32; m; m >>= 1) ssq += __shfl_xor(ssq, m);
    float rn = rsqrtf(ssq);
    yr[lane]      = f2bf(v0 * rn);
    yr[lane + 64] = f2bf(v1 * rn);
}

// ---------------- MFMA S-tile + fused masked-exp loss ----------------
// grid: (N/64 row-blocks) x 4 j-quarters = 512 blocks, 256 threads (4 waves).
// wave w: rows i_wb = rb + (w&1)*32 .. +32, cols quadrant cq = (w>>1)*64.
// Waves (w, w^2) share rows but cover different column halves -> combine
// their per-row partials through LDS before the single global write (R2 bug
// was both waves writing the same pos_part/den_part slot -> denom halved).
__global__ __launch_bounds__(256, 2) void loss_mfma_kernel(
    const short* __restrict__ z1, const short* __restrict__ z2,
    const int* __restrict__ ids,
    float* __restrict__ pos_part, float* __restrict__ den_part)
{
    const int t    = threadIdx.x;
    const int w    = t >> 6;
    const int lane = t & 63;
    const int g    = lane >> 4;   // k-group / row-group
    const int c16  = lane & 15;   // fragment row (A) / col (B)

    const int bid = blockIdx.x;
    const int rb  = (bid >> 2) * 64;
    const int jq  = bid & 3;
    const int jbase0 = jq * (N_TOT / 4);

    const int i_wb = rb + (w & 1) * 32;
    const int cq   = (w >> 1) * 64;
    const int seq_i = i_wb >> 9;            // uniform over the wave's 32 rows

    __shared__ float sh_pos[2][64];
    __shared__ float sh_den[2][64];

    // A fragments: 2 row-frags x 4 k-steps, 8 bf16 each (held for whole kernel)
    bf16x8 af[2][4];
    #pragma unroll
    for (int rf = 0; rf < 2; ++rf)
        #pragma unroll
        for (int ks = 0; ks < 4; ++ks)
            af[rf][ks] = *(const bf16x8*)(z1 + (size_t)(i_wb + rf * 16 + c16) * D + ks * 32 + g * 8);

    // per-(rf,reg) row metadata
    int  idi[2][4], idn[2][4], irow[2][4];
    bool two[2][4];
    #pragma unroll
    for (int rf = 0; rf < 2; ++rf)
        #pragma unroll
        for (int r = 0; r < 4; ++r) {
            int i = i_wb + rf * 16 + g * 4 + r;
            irow[rf][r] = i;
            idi[rf][r]  = ids[i];
            idn[rf][r]  = ids[(i + 1) & (N_TOT - 1)];
            two[rf][r]  = ((i & (SEQ_L - 1)) != (SEQ_L - 1));
        }

    float pos_acc[2][4] = {};
    float den_acc[2][4] = {};

    for (int jt = 0; jt < (N_TOT / 4) / 128; ++jt) {
        const int cb = jbase0 + jt * 128 + cq;

        // B fragments: 4 col-frags x 4 k-steps (B = z2^T, so k-contiguous = z2-row-contiguous)
        bf16x8 bf_[4][4];
        int idj[4], jv[4], seqj[4];
        #pragma unroll
        for (int nf = 0; nf < 4; ++nf) {
            jv[nf]   = cb + nf * 16 + c16;
            idj[nf]  = ids[jv[nf]];
            seqj[nf] = jv[nf] >> 9;
            #pragma unroll
            for (int ks = 0; ks < 4; ++ks)
                bf_[nf][ks] = *(const bf16x8*)(z2 + (size_t)(cb + nf * 16 + c16) * D + ks * 32 + g * 8);
        }

        f32x4 acc[2][4] = {};
        #pragma unroll
        for (int ks = 0; ks < 4; ++ks)
            #pragma unroll
            for (int rf = 0; rf < 2; ++rf)
                #pragma unroll
                for (int nf = 0; nf < 4; ++nf)
                    acc[rf][nf] = __builtin_amdgcn_mfma_f32_16x16x32_bf16(
                        af[rf][ks], bf_[nf][ks], acc[rf][nf], 0, 0, 0);

        // fused epilogue: C/D layout col=lane&15, row=(lane>>4)*4+reg
        #pragma unroll
        for (int rf = 0; rf < 2; ++rf)
            #pragma unroll
            for (int nf = 0; nf < 4; ++nf)
                #pragma unroll
                for (int r = 0; r < 4; ++r) {
                    float s = acc[rf][nf][r];
                    int   i = irow[rf][r];
                    bool eq  = (jv[nf] == i);
                    bool eq2 = two[rf][r] && (jv[nf] == i + 1);
                    pos_acc[rf][r] += (eq || eq2) ? s : 0.f;
                    bool n1 = (idj[nf] != idi[rf][r]);
                    bool m  = two[rf][r]
                            ? (n1 && (idj[nf] != idn[rf][r]) && (seqj[nf] != seq_i))
                            : n1;
                    m = m || eq || eq2;
                    den_acc[rf][r] += m ? __expf(s) : 0.f;
                }
    }

    // reduce over the 16 lanes of each k-group (cols); lane c16==0 holds 8 rows
    #pragma unroll
    for (int rf = 0; rf < 2; ++rf)
        #pragma unroll
        for (int r = 0; r < 4; ++r) {
            float p = pos_acc[rf][r], dsum = den_acc[rf][r];
            #pragma unroll
            for (int m = 8; m; m >>= 1) {
                p    += __shfl_xor(p, m);
                dsum += __shfl_xor(dsum, m);
            }
            if (c16 == 0) {
                int rr = (w & 1) * 32 + rf * 16 + g * 4 + r;   // row within block
                sh_pos[w >> 1][rr] = p;
                sh_den[w >> 1][rr] = dsum;
            }
        }
    __syncthreads();

    // combine the two column-halves, single write per (quarter, row)
    if (t < 64) {
        pos_part[jq * N_TOT + rb + t] = sh_pos[0][t] + sh_pos[1][t];
        den_part[jq * N_TOT + rb + t] = sh_den[0][t] + sh_den[1][t];
    }
}

// ---------------- combine per-quarter partials -> scalar loss ----------------
__global__ __launch_bounds__(1024) void loss_finish_kernel(
    const float* __restrict__ pos_part, const float* __restrict__ den_part,
    float* __restrict__ out)
{
    const int t = threadIdx.x;
    float v = 0.f;
    for (int k = 0; k < N_TOT / 1024; ++k) {
        int row = t + k * 1024;
        float pos = 0.f, den = 0.f;
        #pragma unroll
        for (int q = 0; q < 4; ++q) {
            pos += pos_part[q * N_TOT + row];
            den += den_part[q * N_TOT + row];
        }
        bool two = ((row & (SEQ_L - 1)) != (SEQ_L - 1));
        float npos = two ? 2.f : 1.f;
        v += -(pos - logf(den)) / npos;
    }
    #pragma unroll
    for (int m = 32; m; m >>= 1) v += __shfl_xor(v, m);
    __shared__ float red[16];
    if ((t & 63) == 0) red[t >> 6] = v;
    __syncthreads();
    if (t == 0) {
        float tot = 0.f;
        #pragma unroll
        for (int i = 0; i < 16; ++i) tot += red[i];
        out[0] = tot / (float)N_TOT;
    }
}

extern "C" void kernel_launch(void* const* d_in, const int* in_sizes, int n_in,
                              void* d_out, int out_size, void* d_ws, size_t ws_size,
                              hipStream_t stream)
{
    const int*   ids   = (const int*)d_in[0];
    const float* x1    = (const float*)d_in[2];
    const float* x2    = (const float*)d_in[3];
    const float* w1    = (const float*)d_in[4];
    const float* b1    = (const float*)d_in[5];
    const float* w2    = (const float*)d_in[6];
    const float* b2    = (const float*)d_in[7];
    const float* gamma = (const float*)d_in[8];
    const float* beta  = (const float*)d_in[9];

    char* ws = (char*)d_ws;
    unsigned short* z1b = (unsigned short*)ws;                       // N*D bf16 (2MB)
    unsigned short* z2b = (unsigned short*)(ws + 2 * 1024 * 1024);   // 2MB
    float* mu1 = (float*)(ws + 4 * 1024 * 1024);
    float* sc1 = mu1 + D;
    float* mu2 = sc1 + D;
    float* sc2 = mu2 + D;
    float* pos_part = sc2 + D;                                       // 4*N floats
    float* den_part = pos_part + 4 * N_TOT;                          // 4*N floats

    mlp_kernel<<<N_TOT / 8, 256, 0, stream>>>(x1, w1, b1, w2, b2, z1b);
    mlp_kernel<<<N_TOT / 8, 256, 0, stream>>>(x2, w1, b1, w2, b2, z2b);
    bn_stats_kernel<<<D, 256, 0, stream>>>(z1b, gamma, mu1, sc1);
    bn_stats_kernel<<<D, 256, 0, stream>>>(z2b, gamma, mu2, sc2);
    bn_l2_kernel<<<N_TOT / 4, 256, 0, stream>>>(z1b, mu1, sc1, beta);
    bn_l2_kernel<<<N_TOT / 4, 256, 0, stream>>>(z2b, mu2, sc2, beta);
    loss_mfma_kernel<<<512, 256, 0, stream>>>((const short*)z1b, (const short*)z2b,
                                              ids, pos_part, den_part);
    loss_finish_kernel<<<1, 1024, 0, stream>>>(pos_part, den_part, (float*)d_out);
}

// Round 6
// 192.435 us; speedup vs baseline: 4.9857x; 1.1411x over previous
//
#include <hip/hip_runtime.h>

#define N_TOT 8192
#define SEQ_L 512
#define D 128
#define NCHUNK 16
#define CHUNK (N_TOT / NCHUNK)   // 512 cols per j-chunk

using bf16x8  = __attribute__((ext_vector_type(8))) short;
using f32x4   = __attribute__((ext_vector_type(4))) float;
using ushort8 = __attribute__((ext_vector_type(8))) unsigned short;

static __device__ __forceinline__ unsigned short f2bf(float f) {
    unsigned int u = __float_as_uint(f);
    u = (u + 0x7FFFu + ((u >> 16) & 1u)) >> 16;
    return (unsigned short)u;
}
static __device__ __forceinline__ float bf2f(unsigned short h) {
    return __uint_as_float(((unsigned int)h) << 16);
}

// ---------------- MLP both tensors: y = relu(x @ w1^T + b1) @ w2^T + b2 (bf16 out) ----------------
__global__ __launch_bounds__(256) void mlp_kernel(
    const float* __restrict__ x1, const float* __restrict__ x2,
    const float* __restrict__ w1, const float* __restrict__ b1,
    const float* __restrict__ w2, const float* __restrict__ b2,
    unsigned short* __restrict__ z1, unsigned short* __restrict__ z2)
{
    __shared__ float xs[8][D];
    __shared__ float hs[8][256];
    const int t = threadIdx.x;
    const int tensor = blockIdx.x >> 10;
    const int r0 = (blockIdx.x & 1023) * 8;
    const float* __restrict__ x = tensor ? x2 : x1;
    unsigned short* __restrict__ y = tensor ? z2 : z1;

    {
        const float4* xv = (const float4*)(x + (size_t)r0 * D);
        float4 v = xv[t];
        int rr = t >> 5, cc = (t & 31) << 2;
        xs[rr][cc + 0] = v.x; xs[rr][cc + 1] = v.y;
        xs[rr][cc + 2] = v.z; xs[rr][cc + 3] = v.w;
    }
    __syncthreads();

    {   // hidden: thread t owns hidden unit t for all 8 rows
        const float4* w1v = (const float4*)(w1 + t * D);
        float bb = b1[t];
        float acc[8];
        #pragma unroll
        for (int r = 0; r < 8; ++r) acc[r] = bb;
        for (int d4 = 0; d4 < D / 4; ++d4) {
            float4 wv = w1v[d4];
            #pragma unroll
            for (int r = 0; r < 8; ++r) {
                acc[r] = fmaf(xs[r][d4 * 4 + 0], wv.x, acc[r]);
                acc[r] = fmaf(xs[r][d4 * 4 + 1], wv.y, acc[r]);
                acc[r] = fmaf(xs[r][d4 * 4 + 2], wv.z, acc[r]);
                acc[r] = fmaf(xs[r][d4 * 4 + 3], wv.w, acc[r]);
            }
        }
        #pragma unroll
        for (int r = 0; r < 8; ++r) hs[r][t] = fmaxf(acc[r], 0.f);
    }
    __syncthreads();

    {   // output: thread t owns col (t&127), rows (t>>7)*4 .. +3
        int col = t & 127;
        int rb = (t >> 7) << 2;
        const float4* w2v = (const float4*)(w2 + col * 256);
        float bb = b2[col];
        float acc[4] = {bb, bb, bb, bb};
        for (int k4 = 0; k4 < 64; ++k4) {
            float4 wv = w2v[k4];
            #pragma unroll
            for (int r = 0; r < 4; ++r) {
                acc[r] = fmaf(hs[rb + r][k4 * 4 + 0], wv.x, acc[r]);
                acc[r] = fmaf(hs[rb + r][k4 * 4 + 1], wv.y, acc[r]);
                acc[r] = fmaf(hs[rb + r][k4 * 4 + 2], wv.z, acc[r]);
                acc[r] = fmaf(hs[rb + r][k4 * 4 + 3], wv.w, acc[r]);
            }
        }
        #pragma unroll
        for (int r = 0; r < 4; ++r) y[(size_t)(r0 + rb + r) * D + col] = f2bf(acc[r]);
    }
}

// ---------------- BN partial sums: coalesced ushort8 slabs ----------------
// grid 128: tensor = bid>>6, slab = bid&63 (128 rows each). 256 threads:
// rowg = t>>4 (16 row-threads), colg = t&15 (8 cols each).
__global__ __launch_bounds__(256) void bn_partial_kernel(
    const unsigned short* __restrict__ z1, const unsigned short* __restrict__ z2,
    float* __restrict__ part_s, float* __restrict__ part_ss)
{
    const int t = threadIdx.x;
    const int tensor = blockIdx.x >> 6;
    const int slab = blockIdx.x & 63;
    const int r0 = slab * 128;
    const unsigned short* __restrict__ z = tensor ? z2 : z1;

    const int rowg = t >> 4;
    const int colg = t & 15;

    float s[8] = {}, ss[8] = {};
    for (int it = 0; it < 8; ++it) {
        int row = r0 + rowg + it * 16;
        ushort8 v = *(const ushort8*)(z + (size_t)row * D + colg * 8);
        #pragma unroll
        for (int c = 0; c < 8; ++c) {
            float f = bf2f(v[c]);
            s[c] += f; ss[c] += f * f;
        }
    }

    __shared__ float sh_s[16][D];
    __shared__ float sh_ss[16][D];
    #pragma unroll
    for (int c = 0; c < 8; ++c) {
        sh_s[rowg][colg * 8 + c]  = s[c];
        sh_ss[rowg][colg * 8 + c] = ss[c];
    }
    for (int off = 8; off; off >>= 1) {
        __syncthreads();
        if (rowg < off) {
            #pragma unroll
            for (int c = 0; c < 8; ++c) {
                sh_s[rowg][colg * 8 + c]  += sh_s[rowg + off][colg * 8 + c];
                sh_ss[rowg][colg * 8 + c] += sh_ss[rowg + off][colg * 8 + c];
            }
        }
    }
    __syncthreads();
    if (t < D) {
        part_s[((size_t)tensor * 64 + slab) * D + t]  = sh_s[0][t];
        part_ss[((size_t)tensor * 64 + slab) * D + t] = sh_ss[0][t];
    }
}

// ---------------- BN reduce: 1 block; thread t -> (tensor=t>>7, col=t&127) ----------------
__global__ __launch_bounds__(256) void bn_reduce_kernel(
    const float* __restrict__ part_s, const float* __restrict__ part_ss,
    const float* __restrict__ gamma,
    float* __restrict__ mu, float* __restrict__ sc)
{
    const int t = threadIdx.x;
    const int tensor = t >> 7;
    const int col = t & 127;
    float s = 0.f, ss = 0.f;
    for (int slab = 0; slab < 64; ++slab) {
        s  += part_s[((size_t)tensor * 64 + slab) * D + col];
        ss += part_ss[((size_t)tensor * 64 + slab) * D + col];
    }
    float m = s / (float)N_TOT;
    float var = ss / (float)N_TOT - m * m;
    mu[tensor * D + col] = m;
    sc[tensor * D + col] = gamma[col] * rsqrtf(var + 1e-5f);
}

// ---------------- BN apply + L2 normalize, both tensors, 1 wave/row ----------------
__global__ __launch_bounds__(256) void bn_l2_kernel(
    unsigned short* __restrict__ z1, unsigned short* __restrict__ z2,
    const float* __restrict__ mu, const float* __restrict__ sc,
    const float* __restrict__ beta)
{
    const int t = threadIdx.x;
    const int tensor = blockIdx.x >> 11;
    const int row = (blockIdx.x & 2047) * 4 + (t >> 6);
    const int lane = t & 63;
    unsigned short* __restrict__ yr = (tensor ? z2 : z1) + (size_t)row * D;
    const float* __restrict__ mub = mu + tensor * D;
    const float* __restrict__ scb = sc + tensor * D;

    ushort2 v = ((const ushort2*)yr)[lane];
    float2 m2 = ((const float2*)mub)[lane];
    float2 s2 = ((const float2*)scb)[lane];
    float2 b2 = ((const float2*)beta)[lane];
    float v0 = (bf2f(v.x) - m2.x) * s2.x + b2.x;
    float v1 = (bf2f(v.y) - m2.y) * s2.y + b2.y;
    float ssq = v0 * v0 + v1 * v1;
    #pragma unroll
    for (int m = 32; m; m >>= 1) ssq += __shfl_xor(ssq, m);
    float rn = rsqrtf(ssq);
    ushort2 o; o.x = f2bf(v0 * rn); o.y = f2bf(v1 * rn);
    ((ushort2*)yr)[lane] = o;
}

// ---------------- MFMA S-tile + fused masked-exp loss ----------------
// grid: 128 row-blocks x 16 j-chunks = 2048 blocks, 4 waves each.
// wave w: rows i_wb = rb + (w&1)*32, col quadrant cq = (w>>1)*64 within each 128-tile.
// chunk = bid&15 -> all blocks of a chunk land on XCD chunk%8 (L2-hot z2 chunk).
__global__ __launch_bounds__(256) void loss_mfma_kernel(
    const short* __restrict__ z1, const short* __restrict__ z2,
    const int* __restrict__ ids,
    float* __restrict__ pos_part, float* __restrict__ den_part)
{
    const int t    = threadIdx.x;
    const int w    = t >> 6;
    const int lane = t & 63;
    const int g    = lane >> 4;
    const int c16  = lane & 15;

    const int bid   = blockIdx.x;
    const int chunk = bid & (NCHUNK - 1);
    const int rb    = (bid >> 4) * 64;
    const int jbase = chunk * CHUNK;

    const int i_wb  = rb + (w & 1) * 32;
    const int cq    = (w >> 1) * 64;
    const int seq_i = i_wb >> 9;   // uniform over the wave's 32 rows

    __shared__ float sh_pos[2][64];
    __shared__ float sh_den[2][64];

    // A fragments: 2 row-frags x 4 k-steps
    bf16x8 af[2][4];
    #pragma unroll
    for (int rf = 0; rf < 2; ++rf)
        #pragma unroll
        for (int ks = 0; ks < 4; ++ks)
            af[rf][ks] = *(const bf16x8*)(z1 + (size_t)(i_wb + rf * 16 + c16) * D + ks * 32 + g * 8);

    // per-(rf,reg) row metadata (+ sentinel-folded fast-path values)
    int  idi[2][4], idn[2][4], irow[2][4], idn_s[2][4], seq_s[2][4];
    bool two[2][4];
    #pragma unroll
    for (int rf = 0; rf < 2; ++rf)
        #pragma unroll
        for (int r = 0; r < 4; ++r) {
            int i = i_wb + rf * 16 + g * 4 + r;
            irow[rf][r] = i;
            idi[rf][r]  = ids[i];
            idn[rf][r]  = ids[(i + 1) & (N_TOT - 1)];
            bool tw     = ((i & (SEQ_L - 1)) != (SEQ_L - 1));
            two[rf][r]  = tw;
            idn_s[rf][r] = tw ? idn[rf][r] : idi[rf][r];
            seq_s[rf][r] = tw ? seq_i : -1;
        }

    float pos_acc[2][4] = {};
    float den_acc[2][4] = {};

    #pragma unroll 1
    for (int jt = 0; jt < CHUNK / 128; ++jt) {
        const int cb = jbase + jt * 128 + cq;

        bf16x8 bf_[4][4];
        int idj[4], jv[4], seqj[4];
        #pragma unroll
        for (int nf = 0; nf < 4; ++nf) {
            jv[nf]   = cb + nf * 16 + c16;
            idj[nf]  = ids[jv[nf]];
            seqj[nf] = jv[nf] >> 9;
            #pragma unroll
            for (int ks = 0; ks < 4; ++ks)
                bf_[nf][ks] = *(const bf16x8*)(z2 + (size_t)(cb + nf * 16 + c16) * D + ks * 32 + g * 8);
        }

        f32x4 acc[2][4] = {};
        #pragma unroll
        for (int ks = 0; ks < 4; ++ks)
            #pragma unroll
            for (int rf = 0; rf < 2; ++rf)
                #pragma unroll
                for (int nf = 0; nf < 4; ++nf)
                    acc[rf][nf] = __builtin_amdgcn_mfma_f32_16x16x32_bf16(
                        af[rf][ks], bf_[nf][ks], acc[rf][nf], 0, 0, 0);

        // epilogue: C/D layout col=lane&15, row=(lane>>4)*4+reg
        #pragma unroll
        for (int rf = 0; rf < 2; ++rf)
            #pragma unroll
            for (int nf = 0; nf < 4; ++nf) {
                int dd = (cb + nf * 16) - (i_wb + rf * 16);
                if (dd >= -15 && dd <= 16) {
                    // possible-diagonal tile: full path (identical to verified R3 logic)
                    #pragma unroll
                    for (int r = 0; r < 4; ++r) {
                        float s = acc[rf][nf][r];
                        int   i = irow[rf][r];
                        bool eq  = (jv[nf] == i);
                        bool eq2 = two[rf][r] && (jv[nf] == i + 1);
                        pos_acc[rf][r] += (eq || eq2) ? s : 0.f;
                        bool n1 = (idj[nf] != idi[rf][r]);
                        bool m  = two[rf][r]
                                ? (n1 && (idj[nf] != idn[rf][r]) && (seqj[nf] != seq_i))
                                : n1;
                        m = m || eq || eq2;
                        den_acc[rf][r] += m ? __expf(s) : 0.f;
                    }
                } else {
                    // fast path: eq/eq2 impossible; sentinel-folded mask
                    #pragma unroll
                    for (int r = 0; r < 4; ++r) {
                        float s = acc[rf][nf][r];
                        bool m = (idj[nf] != idi[rf][r])
                               & (idj[nf] != idn_s[rf][r])
                               & (seqj[nf] != seq_s[rf][r]);
                        den_acc[rf][r] += m ? __expf(s) : 0.f;
                    }
                }
            }
    }

    // 16-lane column reduce; lane c16==0 holds 8 rows
    #pragma unroll
    for (int rf = 0; rf < 2; ++rf)
        #pragma unroll
        for (int r = 0; r < 4; ++r) {
            float p = pos_acc[rf][r], dsum = den_acc[rf][r];
            #pragma unroll
            for (int m = 8; m; m >>= 1) {
                p    += __shfl_xor(p, m);
                dsum += __shfl_xor(dsum, m);
            }
            if (c16 == 0) {
                int rr = (w & 1) * 32 + rf * 16 + g * 4 + r;
                sh_pos[w >> 1][rr] = p;
                sh_den[w >> 1][rr] = dsum;
            }
        }
    __syncthreads();

    if (t < 64) {
        pos_part[chunk * N_TOT + rb + t] = sh_pos[0][t] + sh_pos[1][t];
        den_part[chunk * N_TOT + rb + t] = sh_den[0][t] + sh_den[1][t];
    }
}

// ---------------- combine per-chunk partials -> scalar loss ----------------
__global__ __launch_bounds__(1024) void loss_finish_kernel(
    const float* __restrict__ pos_part, const float* __restrict__ den_part,
    float* __restrict__ out)
{
    const int t = threadIdx.x;
    float v = 0.f;
    for (int k = 0; k < N_TOT / 1024; ++k) {
        int row = t + k * 1024;
        float pos = 0.f, den = 0.f;
        #pragma unroll
        for (int q = 0; q < NCHUNK; ++q) {
            pos += pos_part[q * N_TOT + row];
            den += den_part[q * N_TOT + row];
        }
        bool two = ((row & (SEQ_L - 1)) != (SEQ_L - 1));
        float npos = two ? 2.f : 1.f;
        v += -(pos - logf(den)) / npos;
    }
    #pragma unroll
    for (int m = 32; m; m >>= 1) v += __shfl_xor(v, m);
    __shared__ float red[16];
    if ((t & 63) == 0) red[t >> 6] = v;
    __syncthreads();
    if (t == 0) {
        float tot = 0.f;
        #pragma unroll
        for (int i = 0; i < 16; ++i) tot += red[i];
        out[0] = tot / (float)N_TOT;
    }
}

extern "C" void kernel_launch(void* const* d_in, const int* in_sizes, int n_in,
                              void* d_out, int out_size, void* d_ws, size_t ws_size,
                              hipStream_t stream)
{
    const int*   ids   = (const int*)d_in[0];
    const float* x1    = (const float*)d_in[2];
    const float* x2    = (const float*)d_in[3];
    const float* w1    = (const float*)d_in[4];
    const float* b1    = (const float*)d_in[5];
    const float* w2    = (const float*)d_in[6];
    const float* b2    = (const float*)d_in[7];
    const float* gamma = (const float*)d_in[8];
    const float* beta  = (const float*)d_in[9];

    char* ws = (char*)d_ws;
    unsigned short* z1b = (unsigned short*)ws;                        // 2MB
    unsigned short* z2b = (unsigned short*)(ws + (2u << 20));         // 2MB
    float* part_s  = (float*)(ws + (4u << 20));                       // 2*64*128 f = 64KB
    float* part_ss = part_s + 2 * 64 * D;                             // 64KB
    float* mu      = part_ss + 2 * 64 * D;                            // 256 f
    float* sc      = mu + 2 * D;                                      // 256 f
    float* pos_part = sc + 2 * D;                                     // 16*N f = 512KB
    float* den_part = pos_part + NCHUNK * N_TOT;                      // 512KB

    mlp_kernel<<<2048, 256, 0, stream>>>(x1, x2, w1, b1, w2, b2, z1b, z2b);
    bn_partial_kernel<<<128, 256, 0, stream>>>(z1b, z2b, part_s, part_ss);
    bn_reduce_kernel<<<1, 256, 0, stream>>>(part_s, part_ss, gamma, mu, sc);
    bn_l2_kernel<<<4096, 256, 0, stream>>>(z1b, z2b, mu, sc, beta);
    loss_mfma_kernel<<<2048, 256, 0, stream>>>((const short*)z1b, (const short*)z2b,
                                               ids, pos_part, den_part);
    loss_finish_kernel<<<1, 1024, 0, stream>>>(pos_part, den_part, (float*)d_out);
}

// Round 7
// 132.213 us; speedup vs baseline: 7.2567x; 1.4555x over previous
//
#include <hip/hip_runtime.h>

#define N_TOT 8192
#define SEQ_L 512
#define D 128
#define NCHUNK 16
#define CHUNK (N_TOT / NCHUNK)   // 512 cols per j-chunk

using bf16x8  = __attribute__((ext_vector_type(8))) short;
using f32x4   = __attribute__((ext_vector_type(4))) float;
using ushort8 = __attribute__((ext_vector_type(8))) unsigned short;

static __device__ __forceinline__ unsigned short f2bf(float f) {
    unsigned int u = __float_as_uint(f);
    u = (u + 0x7FFFu + ((u >> 16) & 1u)) >> 16;
    return (unsigned short)u;
}
static __device__ __forceinline__ float bf2f(unsigned short h) {
    return __uint_as_float(((unsigned int)h) << 16);
}

// ---------------- one-shot: convert w1/w2 to bf16 ----------------
__global__ __launch_bounds__(256) void convert_w_kernel(
    const float* __restrict__ w1, const float* __restrict__ w2,
    unsigned short* __restrict__ w1b, unsigned short* __restrict__ w2b)
{
    int idx = blockIdx.x * 256 + threadIdx.x;        // 16384 float4s total
    const float* src = (idx < 8192) ? w1 : w2;
    unsigned short* dst = (idx < 8192) ? w1b : w2b;
    int off = ((idx < 8192) ? idx : idx - 8192) * 4;
    float4 v = *(const float4*)(src + off);
    ushort4 o;
    o.x = f2bf(v.x); o.y = f2bf(v.y); o.z = f2bf(v.z); o.w = f2bf(v.w);
    *(ushort4*)(dst + off) = o;
}

// ---------------- MFMA MLP: z = relu(x @ w1^T + b1) @ w2^T + b2 (bf16 out) ----------------
// 16 rows/block, 1024 blocks (tensor = bid>>9). 4 waves: wave w owns
// layer-1 cols w*64..+64 and layer-2 cols w*32..+32. A-frag row = c16,
// k = ks*32 + g*8 (same verified fragment pattern as loss_mfma_kernel);
// C/D: col = c16, row = g*4 + r.
__global__ __launch_bounds__(256) void mlp_mfma_kernel(
    const float* __restrict__ x1, const float* __restrict__ x2,
    const unsigned short* __restrict__ w1b, const float* __restrict__ b1,
    const unsigned short* __restrict__ w2b, const float* __restrict__ b2,
    unsigned short* __restrict__ z1, unsigned short* __restrict__ z2)
{
    __shared__ unsigned short hsh[16][264];   // pad 256->264: layer-2 reads 2-way (free)
    const int t = threadIdx.x;
    const int w = t >> 6;
    const int lane = t & 63;
    const int g = lane >> 4;
    const int c16 = lane & 15;
    const int tensor = blockIdx.x >> 9;
    const int r0 = (blockIdx.x & 511) * 16;
    const float* __restrict__ x = tensor ? x2 : x1;
    unsigned short* __restrict__ z = tensor ? z2 : z1;

    // ---- layer 1: h[16][256], this wave cols w*64..+64 ----
    bf16x8 af[4];
    #pragma unroll
    for (int ks = 0; ks < 4; ++ks) {
        const float* xp = x + (size_t)(r0 + c16) * D + ks * 32 + g * 8;
        float4 u0 = *(const float4*)xp;
        float4 u1 = *(const float4*)(xp + 4);
        bf16x8 a;
        a[0] = f2bf(u0.x); a[1] = f2bf(u0.y); a[2] = f2bf(u0.z); a[3] = f2bf(u0.w);
        a[4] = f2bf(u1.x); a[5] = f2bf(u1.y); a[6] = f2bf(u1.z); a[7] = f2bf(u1.w);
        af[ks] = a;
    }
    f32x4 acc1[4] = {};
    #pragma unroll
    for (int ks = 0; ks < 4; ++ks)
        #pragma unroll
        for (int nf = 0; nf < 4; ++nf) {
            int n = w * 64 + nf * 16 + c16;   // hidden unit = w1 row
            bf16x8 b = *(const bf16x8*)(w1b + (size_t)n * D + ks * 32 + g * 8);
            acc1[nf] = __builtin_amdgcn_mfma_f32_16x16x32_bf16(af[ks], b, acc1[nf], 0, 0, 0);
        }
    #pragma unroll
    for (int nf = 0; nf < 4; ++nf) {
        float bb = b1[w * 64 + nf * 16 + c16];
        #pragma unroll
        for (int r = 0; r < 4; ++r) {
            float v = fmaxf(acc1[nf][r] + bb, 0.f);
            hsh[g * 4 + r][w * 64 + nf * 16 + c16] = f2bf(v);
        }
    }
    __syncthreads();

    // ---- layer 2: y[16][128], this wave cols w*32..+32, K=256 ----
    f32x4 acc2[2] = {};
    #pragma unroll
    for (int ks = 0; ks < 8; ++ks) {
        bf16x8 a = *(const bf16x8*)(&hsh[c16][ks * 32 + g * 8]);
        #pragma unroll
        for (int nf = 0; nf < 2; ++nf) {
            int n = w * 32 + nf * 16 + c16;   // output col = w2 row
            bf16x8 b = *(const bf16x8*)(w2b + (size_t)n * 256 + ks * 32 + g * 8);
            acc2[nf] = __builtin_amdgcn_mfma_f32_16x16x32_bf16(a, b, acc2[nf], 0, 0, 0);
        }
    }
    #pragma unroll
    for (int nf = 0; nf < 2; ++nf) {
        float bb = b2[w * 32 + nf * 16 + c16];
        #pragma unroll
        for (int r = 0; r < 4; ++r)
            z[(size_t)(r0 + g * 4 + r) * D + w * 32 + nf * 16 + c16] = f2bf(acc2[nf][r] + bb);
    }
}

// ---------------- BN partial sums: coalesced ushort8 slabs ----------------
__global__ __launch_bounds__(256) void bn_partial_kernel(
    const unsigned short* __restrict__ z1, const unsigned short* __restrict__ z2,
    float* __restrict__ part_s, float* __restrict__ part_ss)
{
    const int t = threadIdx.x;
    const int tensor = blockIdx.x >> 6;
    const int slab = blockIdx.x & 63;
    const int r0 = slab * 128;
    const unsigned short* __restrict__ z = tensor ? z2 : z1;

    const int rowg = t >> 4;
    const int colg = t & 15;

    float s[8] = {}, ss[8] = {};
    for (int it = 0; it < 8; ++it) {
        int row = r0 + rowg + it * 16;
        ushort8 v = *(const ushort8*)(z + (size_t)row * D + colg * 8);
        #pragma unroll
        for (int c = 0; c < 8; ++c) {
            float f = bf2f(v[c]);
            s[c] += f; ss[c] += f * f;
        }
    }

    __shared__ float sh_s[16][D];
    __shared__ float sh_ss[16][D];
    #pragma unroll
    for (int c = 0; c < 8; ++c) {
        sh_s[rowg][colg * 8 + c]  = s[c];
        sh_ss[rowg][colg * 8 + c] = ss[c];
    }
    for (int off = 8; off; off >>= 1) {
        __syncthreads();
        if (rowg < off) {
            #pragma unroll
            for (int c = 0; c < 8; ++c) {
                sh_s[rowg][colg * 8 + c]  += sh_s[rowg + off][colg * 8 + c];
                sh_ss[rowg][colg * 8 + c] += sh_ss[rowg + off][colg * 8 + c];
            }
        }
    }
    __syncthreads();
    if (t < D) {
        part_s[((size_t)tensor * 64 + slab) * D + t]  = sh_s[0][t];
        part_ss[((size_t)tensor * 64 + slab) * D + t] = sh_ss[0][t];
    }
}

// ---------------- BN reduce ----------------
__global__ __launch_bounds__(256) void bn_reduce_kernel(
    const float* __restrict__ part_s, const float* __restrict__ part_ss,
    const float* __restrict__ gamma,
    float* __restrict__ mu, float* __restrict__ sc)
{
    const int t = threadIdx.x;
    const int tensor = t >> 7;
    const int col = t & 127;
    float s = 0.f, ss = 0.f;
    for (int slab = 0; slab < 64; ++slab) {
        s  += part_s[((size_t)tensor * 64 + slab) * D + col];
        ss += part_ss[((size_t)tensor * 64 + slab) * D + col];
    }
    float m = s / (float)N_TOT;
    float var = ss / (float)N_TOT - m * m;
    mu[tensor * D + col] = m;
    sc[tensor * D + col] = gamma[col] * rsqrtf(var + 1e-5f);
}

// ---------------- BN apply + L2 normalize ----------------
__global__ __launch_bounds__(256) void bn_l2_kernel(
    unsigned short* __restrict__ z1, unsigned short* __restrict__ z2,
    const float* __restrict__ mu, const float* __restrict__ sc,
    const float* __restrict__ beta)
{
    const int t = threadIdx.x;
    const int tensor = blockIdx.x >> 11;
    const int row = (blockIdx.x & 2047) * 4 + (t >> 6);
    const int lane = t & 63;
    unsigned short* __restrict__ yr = (tensor ? z2 : z1) + (size_t)row * D;
    const float* __restrict__ mub = mu + tensor * D;
    const float* __restrict__ scb = sc + tensor * D;

    ushort2 v = ((const ushort2*)yr)[lane];
    float2 m2 = ((const float2*)mub)[lane];
    float2 s2 = ((const float2*)scb)[lane];
    float2 b2 = ((const float2*)beta)[lane];
    float v0 = (bf2f(v.x) - m2.x) * s2.x + b2.x;
    float v1 = (bf2f(v.y) - m2.y) * s2.y + b2.y;
    float ssq = v0 * v0 + v1 * v1;
    #pragma unroll
    for (int m = 32; m; m >>= 1) ssq += __shfl_xor(ssq, m);
    float rn = rsqrtf(ssq);
    ushort2 o; o.x = f2bf(v0 * rn); o.y = f2bf(v1 * rn);
    ((ushort2*)yr)[lane] = o;
}

// ---------------- MFMA S-tile + fused masked-exp loss ----------------
__global__ __launch_bounds__(256) void loss_mfma_kernel(
    const short* __restrict__ z1, const short* __restrict__ z2,
    const int* __restrict__ ids,
    float* __restrict__ pos_part, float* __restrict__ den_part)
{
    const int t    = threadIdx.x;
    const int w    = t >> 6;
    const int lane = t & 63;
    const int g    = lane >> 4;
    const int c16  = lane & 15;

    const int bid   = blockIdx.x;
    const int chunk = bid & (NCHUNK - 1);
    const int rb    = (bid >> 4) * 64;
    const int jbase = chunk * CHUNK;

    const int i_wb  = rb + (w & 1) * 32;
    const int cq    = (w >> 1) * 64;
    const int seq_i = i_wb >> 9;

    __shared__ float sh_pos[2][64];
    __shared__ float sh_den[2][64];

    bf16x8 af[2][4];
    #pragma unroll
    for (int rf = 0; rf < 2; ++rf)
        #pragma unroll
        for (int ks = 0; ks < 4; ++ks)
            af[rf][ks] = *(const bf16x8*)(z1 + (size_t)(i_wb + rf * 16 + c16) * D + ks * 32 + g * 8);

    int  idi[2][4], idn[2][4], irow[2][4], idn_s[2][4], seq_s[2][4];
    bool two[2][4];
    #pragma unroll
    for (int rf = 0; rf < 2; ++rf)
        #pragma unroll
        for (int r = 0; r < 4; ++r) {
            int i = i_wb + rf * 16 + g * 4 + r;
            irow[rf][r] = i;
            idi[rf][r]  = ids[i];
            idn[rf][r]  = ids[(i + 1) & (N_TOT - 1)];
            bool tw     = ((i & (SEQ_L - 1)) != (SEQ_L - 1));
            two[rf][r]  = tw;
            idn_s[rf][r] = tw ? idn[rf][r] : idi[rf][r];
            seq_s[rf][r] = tw ? seq_i : -1;
        }

    float pos_acc[2][4] = {};
    float den_acc[2][4] = {};

    #pragma unroll 1
    for (int jt = 0; jt < CHUNK / 128; ++jt) {
        const int cb = jbase + jt * 128 + cq;

        bf16x8 bf_[4][4];
        int idj[4], jv[4], seqj[4];
        #pragma unroll
        for (int nf = 0; nf < 4; ++nf) {
            jv[nf]   = cb + nf * 16 + c16;
            idj[nf]  = ids[jv[nf]];
            seqj[nf] = jv[nf] >> 9;
            #pragma unroll
            for (int ks = 0; ks < 4; ++ks)
                bf_[nf][ks] = *(const bf16x8*)(z2 + (size_t)(cb + nf * 16 + c16) * D + ks * 32 + g * 8);
        }

        f32x4 acc[2][4] = {};
        #pragma unroll
        for (int ks = 0; ks < 4; ++ks)
            #pragma unroll
            for (int rf = 0; rf < 2; ++rf)
                #pragma unroll
                for (int nf = 0; nf < 4; ++nf)
                    acc[rf][nf] = __builtin_amdgcn_mfma_f32_16x16x32_bf16(
                        af[rf][ks], bf_[nf][ks], acc[rf][nf], 0, 0, 0);

        #pragma unroll
        for (int rf = 0; rf < 2; ++rf)
            #pragma unroll
            for (int nf = 0; nf < 4; ++nf) {
                int dd = (cb + nf * 16) - (i_wb + rf * 16);
                if (dd >= -15 && dd <= 16) {
                    #pragma unroll
                    for (int r = 0; r < 4; ++r) {
                        float s = acc[rf][nf][r];
                        int   i = irow[rf][r];
                        bool eq  = (jv[nf] == i);
                        bool eq2 = two[rf][r] && (jv[nf] == i + 1);
                        pos_acc[rf][r] += (eq || eq2) ? s : 0.f;
                        bool n1 = (idj[nf] != idi[rf][r]);
                        bool m  = two[rf][r]
                                ? (n1 && (idj[nf] != idn[rf][r]) && (seqj[nf] != seq_i))
                                : n1;
                        m = m || eq || eq2;
                        den_acc[rf][r] += m ? __expf(s) : 0.f;
                    }
                } else {
                    #pragma unroll
                    for (int r = 0; r < 4; ++r) {
                        float s = acc[rf][nf][r];
                        bool m = (idj[nf] != idi[rf][r])
                               & (idj[nf] != idn_s[rf][r])
                               & (seqj[nf] != seq_s[rf][r]);
                        den_acc[rf][r] += m ? __expf(s) : 0.f;
                    }
                }
            }
    }

    #pragma unroll
    for (int rf = 0; rf < 2; ++rf)
        #pragma unroll
        for (int r = 0; r < 4; ++r) {
            float p = pos_acc[rf][r], dsum = den_acc[rf][r];
            #pragma unroll
            for (int m = 8; m; m >>= 1) {
                p    += __shfl_xor(p, m);
                dsum += __shfl_xor(dsum, m);
            }
            if (c16 == 0) {
                int rr = (w & 1) * 32 + rf * 16 + g * 4 + r;
                sh_pos[w >> 1][rr] = p;
                sh_den[w >> 1][rr] = dsum;
            }
        }
    __syncthreads();

    if (t < 64) {
        pos_part[chunk * N_TOT + rb + t] = sh_pos[0][t] + sh_pos[1][t];
        den_part[chunk * N_TOT + rb + t] = sh_den[0][t] + sh_den[1][t];
    }
}

// ---------------- combine per-chunk partials -> scalar loss ----------------
__global__ __launch_bounds__(1024) void loss_finish_kernel(
    const float* __restrict__ pos_part, const float* __restrict__ den_part,
    float* __restrict__ out)
{
    const int t = threadIdx.x;
    float v = 0.f;
    for (int k = 0; k < N_TOT / 1024; ++k) {
        int row = t + k * 1024;
        float pos = 0.f, den = 0.f;
        #pragma unroll
        for (int q = 0; q < NCHUNK; ++q) {
            pos += pos_part[q * N_TOT + row];
            den += den_part[q * N_TOT + row];
        }
        bool two = ((row & (SEQ_L - 1)) != (SEQ_L - 1));
        float npos = two ? 2.f : 1.f;
        v += -(pos - logf(den)) / npos;
    }
    #pragma unroll
    for (int m = 32; m; m >>= 1) v += __shfl_xor(v, m);
    __shared__ float red[16];
    if ((t & 63) == 0) red[t >> 6] = v;
    __syncthreads();
    if (t == 0) {
        float tot = 0.f;
        #pragma unroll
        for (int i = 0; i < 16; ++i) tot += red[i];
        out[0] = tot / (float)N_TOT;
    }
}

extern "C" void kernel_launch(void* const* d_in, const int* in_sizes, int n_in,
                              void* d_out, int out_size, void* d_ws, size_t ws_size,
                              hipStream_t stream)
{
    const int*   ids   = (const int*)d_in[0];
    const float* x1    = (const float*)d_in[2];
    const float* x2    = (const float*)d_in[3];
    const float* w1    = (const float*)d_in[4];
    const float* b1    = (const float*)d_in[5];
    const float* w2    = (const float*)d_in[6];
    const float* b2    = (const float*)d_in[7];
    const float* gamma = (const float*)d_in[8];
    const float* beta  = (const float*)d_in[9];

    char* ws = (char*)d_ws;
    unsigned short* z1b = (unsigned short*)ws;                        // 2MB
    unsigned short* z2b = (unsigned short*)(ws + (2u << 20));         // 2MB
    float* part_s  = (float*)(ws + (4u << 20));                       // 64KB
    float* part_ss = part_s + 2 * 64 * D;                             // 64KB
    float* mu      = part_ss + 2 * 64 * D;
    float* sc      = mu + 2 * D;
    float* pos_part = sc + 2 * D;                                     // 512KB
    float* den_part = pos_part + NCHUNK * N_TOT;                      // 512KB
    unsigned short* w1b = (unsigned short*)(den_part + NCHUNK * N_TOT); // 64KB
    unsigned short* w2b = w1b + 256 * D;                              // 64KB

    convert_w_kernel<<<64, 256, 0, stream>>>(w1, w2, w1b, w2b);
    mlp_mfma_kernel<<<1024, 256, 0, stream>>>(x1, x2, w1b, b1, w2b, b2, z1b, z2b);
    bn_partial_kernel<<<128, 256, 0, stream>>>(z1b, z2b, part_s, part_ss);
    bn_reduce_kernel<<<1, 256, 0, stream>>>(part_s, part_ss, gamma, mu, sc);
    bn_l2_kernel<<<4096, 256, 0, stream>>>(z1b, z2b, mu, sc, beta);
    loss_mfma_kernel<<<2048, 256, 0, stream>>>((const short*)z1b, (const short*)z2b,
                                               ids, pos_part, den_part);
    loss_finish_kernel<<<1, 1024, 0, stream>>>(pos_part, den_part, (float*)d_out);
}

// Round 8
// 97.585 us; speedup vs baseline: 9.8317x; 1.3548x over previous
//
#include <hip/hip_runtime.h>

#define N_TOT 8192
#define SEQ_L 512
#define D 128
#define NCHUNK 16
#define CHUNK (N_TOT / NCHUNK)   // 512 cols per j-chunk
#define NJT (CHUNK / 64)         // 8 64-col tiles per chunk

using bf16x8  = __attribute__((ext_vector_type(8))) short;
using f32x4   = __attribute__((ext_vector_type(4))) float;
using ushort8 = __attribute__((ext_vector_type(8))) unsigned short;

static __device__ __forceinline__ unsigned short f2bf(float f) {
    unsigned int u = __float_as_uint(f);
    u = (u + 0x7FFFu + ((u >> 16) & 1u)) >> 16;
    return (unsigned short)u;
}
static __device__ __forceinline__ float bf2f(unsigned short h) {
    return __uint_as_float(((unsigned int)h) << 16);
}

// ---------------- one-shot: convert w1/w2 to bf16 ----------------
__global__ __launch_bounds__(256) void convert_w_kernel(
    const float* __restrict__ w1, const float* __restrict__ w2,
    unsigned short* __restrict__ w1b, unsigned short* __restrict__ w2b)
{
    int idx = blockIdx.x * 256 + threadIdx.x;        // 16384 float4s total
    const float* src = (idx < 8192) ? w1 : w2;
    unsigned short* dst = (idx < 8192) ? w1b : w2b;
    int off = ((idx < 8192) ? idx : idx - 8192) * 4;
    float4 v = *(const float4*)(src + off);
    ushort4 o;
    o.x = f2bf(v.x); o.y = f2bf(v.y); o.z = f2bf(v.z); o.w = f2bf(v.w);
    *(ushort4*)(dst + off) = o;
}

// ---------------- MFMA MLP: z = relu(x @ w1^T + b1) @ w2^T + b2 (bf16 out) ----------------
__global__ __launch_bounds__(256) void mlp_mfma_kernel(
    const float* __restrict__ x1, const float* __restrict__ x2,
    const unsigned short* __restrict__ w1b, const float* __restrict__ b1,
    const unsigned short* __restrict__ w2b, const float* __restrict__ b2,
    unsigned short* __restrict__ z1, unsigned short* __restrict__ z2)
{
    __shared__ unsigned short hsh[16][264];   // pad 256->264: layer-2 reads 2-way (free)
    const int t = threadIdx.x;
    const int w = t >> 6;
    const int lane = t & 63;
    const int g = lane >> 4;
    const int c16 = lane & 15;
    const int tensor = blockIdx.x >> 9;
    const int r0 = (blockIdx.x & 511) * 16;
    const float* __restrict__ x = tensor ? x2 : x1;
    unsigned short* __restrict__ z = tensor ? z2 : z1;

    // ---- layer 1: h[16][256], this wave cols w*64..+64 ----
    bf16x8 af[4];
    #pragma unroll
    for (int ks = 0; ks < 4; ++ks) {
        const float* xp = x + (size_t)(r0 + c16) * D + ks * 32 + g * 8;
        float4 u0 = *(const float4*)xp;
        float4 u1 = *(const float4*)(xp + 4);
        bf16x8 a;
        a[0] = f2bf(u0.x); a[1] = f2bf(u0.y); a[2] = f2bf(u0.z); a[3] = f2bf(u0.w);
        a[4] = f2bf(u1.x); a[5] = f2bf(u1.y); a[6] = f2bf(u1.z); a[7] = f2bf(u1.w);
        af[ks] = a;
    }
    f32x4 acc1[4] = {};
    #pragma unroll
    for (int ks = 0; ks < 4; ++ks)
        #pragma unroll
        for (int nf = 0; nf < 4; ++nf) {
            int n = w * 64 + nf * 16 + c16;   // hidden unit = w1 row
            bf16x8 b = *(const bf16x8*)(w1b + (size_t)n * D + ks * 32 + g * 8);
            acc1[nf] = __builtin_amdgcn_mfma_f32_16x16x32_bf16(af[ks], b, acc1[nf], 0, 0, 0);
        }
    #pragma unroll
    for (int nf = 0; nf < 4; ++nf) {
        float bb = b1[w * 64 + nf * 16 + c16];
        #pragma unroll
        for (int r = 0; r < 4; ++r) {
            float v = fmaxf(acc1[nf][r] + bb, 0.f);
            hsh[g * 4 + r][w * 64 + nf * 16 + c16] = f2bf(v);
        }
    }
    __syncthreads();

    // ---- layer 2: y[16][128], this wave cols w*32..+32, K=256 ----
    f32x4 acc2[2] = {};
    #pragma unroll
    for (int ks = 0; ks < 8; ++ks) {
        bf16x8 a = *(const bf16x8*)(&hsh[c16][ks * 32 + g * 8]);
        #pragma unroll
        for (int nf = 0; nf < 2; ++nf) {
            int n = w * 32 + nf * 16 + c16;   // output col = w2 row
            bf16x8 b = *(const bf16x8*)(w2b + (size_t)n * 256 + ks * 32 + g * 8);
            acc2[nf] = __builtin_amdgcn_mfma_f32_16x16x32_bf16(a, b, acc2[nf], 0, 0, 0);
        }
    }
    #pragma unroll
    for (int nf = 0; nf < 2; ++nf) {
        float bb = b2[w * 32 + nf * 16 + c16];
        #pragma unroll
        for (int r = 0; r < 4; ++r)
            z[(size_t)(r0 + g * 4 + r) * D + w * 32 + nf * 16 + c16] = f2bf(acc2[nf][r] + bb);
    }
}

// ---------------- BN partial sums: coalesced ushort8 slabs ----------------
__global__ __launch_bounds__(256) void bn_partial_kernel(
    const unsigned short* __restrict__ z1, const unsigned short* __restrict__ z2,
    float* __restrict__ part_s, float* __restrict__ part_ss)
{
    const int t = threadIdx.x;
    const int tensor = blockIdx.x >> 6;
    const int slab = blockIdx.x & 63;
    const int r0 = slab * 128;
    const unsigned short* __restrict__ z = tensor ? z2 : z1;

    const int rowg = t >> 4;
    const int colg = t & 15;

    float s[8] = {}, ss[8] = {};
    for (int it = 0; it < 8; ++it) {
        int row = r0 + rowg + it * 16;
        ushort8 v = *(const ushort8*)(z + (size_t)row * D + colg * 8);
        #pragma unroll
        for (int c = 0; c < 8; ++c) {
            float f = bf2f(v[c]);
            s[c] += f; ss[c] += f * f;
        }
    }

    __shared__ float sh_s[16][D];
    __shared__ float sh_ss[16][D];
    #pragma unroll
    for (int c = 0; c < 8; ++c) {
        sh_s[rowg][colg * 8 + c]  = s[c];
        sh_ss[rowg][colg * 8 + c] = ss[c];
    }
    for (int off = 8; off; off >>= 1) {
        __syncthreads();
        if (rowg < off) {
            #pragma unroll
            for (int c = 0; c < 8; ++c) {
                sh_s[rowg][colg * 8 + c]  += sh_s[rowg + off][colg * 8 + c];
                sh_ss[rowg][colg * 8 + c] += sh_ss[rowg + off][colg * 8 + c];
            }
        }
    }
    __syncthreads();
    if (t < D) {
        part_s[((size_t)tensor * 64 + slab) * D + t]  = sh_s[0][t];
        part_ss[((size_t)tensor * 64 + slab) * D + t] = sh_ss[0][t];
    }
}

// ---------------- BN reduce ----------------
__global__ __launch_bounds__(256) void bn_reduce_kernel(
    const float* __restrict__ part_s, const float* __restrict__ part_ss,
    const float* __restrict__ gamma,
    float* __restrict__ mu, float* __restrict__ sc)
{
    const int t = threadIdx.x;
    const int tensor = t >> 7;
    const int col = t & 127;
    float s = 0.f, ss = 0.f;
    for (int slab = 0; slab < 64; ++slab) {
        s  += part_s[((size_t)tensor * 64 + slab) * D + col];
        ss += part_ss[((size_t)tensor * 64 + slab) * D + col];
    }
    float m = s / (float)N_TOT;
    float var = ss / (float)N_TOT - m * m;
    mu[tensor * D + col] = m;
    sc[tensor * D + col] = gamma[col] * rsqrtf(var + 1e-5f);
}

// ---------------- BN apply + L2 normalize ----------------
__global__ __launch_bounds__(256) void bn_l2_kernel(
    unsigned short* __restrict__ z1, unsigned short* __restrict__ z2,
    const float* __restrict__ mu, const float* __restrict__ sc,
    const float* __restrict__ beta)
{
    const int t = threadIdx.x;
    const int tensor = blockIdx.x >> 11;
    const int row = (blockIdx.x & 2047) * 4 + (t >> 6);
    const int lane = t & 63;
    unsigned short* __restrict__ yr = (tensor ? z2 : z1) + (size_t)row * D;
    const float* __restrict__ mub = mu + tensor * D;
    const float* __restrict__ scb = sc + tensor * D;

    ushort2 v = ((const ushort2*)yr)[lane];
    float2 m2 = ((const float2*)mub)[lane];
    float2 s2 = ((const float2*)scb)[lane];
    float2 b2 = ((const float2*)beta)[lane];
    float v0 = (bf2f(v.x) - m2.x) * s2.x + b2.x;
    float v1 = (bf2f(v.y) - m2.y) * s2.y + b2.y;
    float ssq = v0 * v0 + v1 * v1;
    #pragma unroll
    for (int m = 32; m; m >>= 1) ssq += __shfl_xor(ssq, m);
    float rn = rsqrtf(ssq);
    ushort2 o; o.x = f2bf(v0 * rn); o.y = f2bf(v1 * rn);
    ((ushort2*)yr)[lane] = o;
}

// ---------------- MFMA S-tile + fused masked-exp loss (2-phase pipelined) ----------------
// grid: 64 row-blocks x 16 chunks = 1024 blocks, 4 waves. Block = 128 rows x
// chunk(512 cols). Wave w owns rows i_wb = rb + w*32 (exclusive -> single
// writer per (chunk,row), no cross-wave combine). Per jt: one 64-col z2 tile
// staged in LDS (double-buffered, reg-staged T14: load next-tile regs early,
// ds_write after epilogue, 1 barrier/jt). XOR swizzle byte^=(row&7)<<4 on
// write AND read -> ds_read_b128 2-way (free).
__global__ __launch_bounds__(256) void loss_mfma_kernel(
    const short* __restrict__ z1, const short* __restrict__ z2,
    const int* __restrict__ ids,
    float* __restrict__ pos_part, float* __restrict__ den_part)
{
    const int t    = threadIdx.x;
    const int w    = t >> 6;
    const int lane = t & 63;
    const int g    = lane >> 4;
    const int c16  = lane & 15;

    const int bid   = blockIdx.x;
    const int chunk = bid & (NCHUNK - 1);
    const int rb    = (bid >> 4) * 128;
    const int jbase = chunk * CHUNK;

    const int i_wb  = rb + w * 32;
    const int seq_i = i_wb >> 9;   // uniform over the wave's 32 rows

    __shared__ __align__(16) unsigned char z2s[2][64 * 256];  // 2 x 16KB tiles

    const int srow = t >> 2;   // staging: thread -> z2 tile row 0..63
    const int sq   = t & 3;    // 16B quarter-of-64B within row

    // A fragments: 2 row-frags x 4 k-steps (held whole kernel)
    bf16x8 af[2][4];
    #pragma unroll
    for (int rf = 0; rf < 2; ++rf)
        #pragma unroll
        for (int ks = 0; ks < 4; ++ks)
            af[rf][ks] = *(const bf16x8*)(z1 + (size_t)(i_wb + rf * 16 + c16) * D + ks * 32 + g * 8);

    // per-(rf,reg) row metadata (+ sentinel-folded fast-path values)
    int  idi[2][4], idn[2][4], irow[2][4], idn_s[2][4], seq_s[2][4];
    bool two[2][4];
    #pragma unroll
    for (int rf = 0; rf < 2; ++rf)
        #pragma unroll
        for (int r = 0; r < 4; ++r) {
            int i = i_wb + rf * 16 + g * 4 + r;
            irow[rf][r] = i;
            idi[rf][r]  = ids[i];
            idn[rf][r]  = ids[(i + 1) & (N_TOT - 1)];
            bool tw     = ((i & (SEQ_L - 1)) != (SEQ_L - 1));
            two[rf][r]  = tw;
            idn_s[rf][r] = tw ? idn[rf][r] : idi[rf][r];
            seq_s[rf][r] = tw ? seq_i : -1;
        }

    // prologue: stage tile 0 into buffer 0
    #pragma unroll
    for (int it = 0; it < 4; ++it) {
        bf16x8 v = *(const bf16x8*)(z2 + (size_t)(jbase + srow) * D + sq * 8 + it * 32);
        int byte = (sq * 16 + it * 64) ^ ((srow & 7) << 4);
        *(bf16x8*)&z2s[0][srow * 256 + byte] = v;
    }
    __syncthreads();

    float pos_acc[2][4] = {};
    float den_acc[2][4] = {};
    int cbuf = 0;

    #pragma unroll 1
    for (int jt = 0; jt < NJT; ++jt) {
        const int cb = jbase + jt * 64;

        // issue next tile's global loads early (consumed by ds_write below)
        bf16x8 stg[4];
        if (jt + 1 < NJT) {
            #pragma unroll
            for (int it = 0; it < 4; ++it)
                stg[it] = *(const bf16x8*)(z2 + (size_t)(cb + 64 + srow) * D + sq * 8 + it * 32);
        }

        int idj[4], jv[4], seqj[4];
        #pragma unroll
        for (int nf = 0; nf < 4; ++nf) {
            jv[nf]   = cb + nf * 16 + c16;
            idj[nf]  = ids[jv[nf]];
            seqj[nf] = jv[nf] >> 9;
        }

        // MFMA over the staged tile: B-frag row = nf*16+c16, k = ks*32+g*8
        f32x4 acc[2][4] = {};
        #pragma unroll
        for (int ks = 0; ks < 4; ++ks)
            #pragma unroll
            for (int nf = 0; nf < 4; ++nf) {
                int r = nf * 16 + c16;
                int byte = (ks * 64 + g * 16) ^ ((r & 7) << 4);
                bf16x8 b = *(const bf16x8*)&z2s[cbuf][r * 256 + byte];
                acc[0][nf] = __builtin_amdgcn_mfma_f32_16x16x32_bf16(af[0][ks], b, acc[0][nf], 0, 0, 0);
                acc[1][nf] = __builtin_amdgcn_mfma_f32_16x16x32_bf16(af[1][ks], b, acc[1][nf], 0, 0, 0);
            }

        // epilogue: C/D layout col=lane&15, row=(lane>>4)*4+reg
        #pragma unroll
        for (int rf = 0; rf < 2; ++rf)
            #pragma unroll
            for (int nf = 0; nf < 4; ++nf) {
                int dd = (cb + nf * 16) - (i_wb + rf * 16);
                if (dd >= -15 && dd <= 16) {
                    // possible-diagonal tile: full path (verified R3 logic)
                    #pragma unroll
                    for (int r = 0; r < 4; ++r) {
                        float s = acc[rf][nf][r];
                        int   i = irow[rf][r];
                        bool eq  = (jv[nf] == i);
                        bool eq2 = two[rf][r] && (jv[nf] == i + 1);
                        pos_acc[rf][r] += (eq || eq2) ? s : 0.f;
                        bool n1 = (idj[nf] != idi[rf][r]);
                        bool m  = two[rf][r]
                                ? (n1 && (idj[nf] != idn[rf][r]) && (seqj[nf] != seq_i))
                                : n1;
                        m = m || eq || eq2;
                        den_acc[rf][r] += m ? __expf(s) : 0.f;
                    }
                } else {
                    // fast path: eq/eq2 impossible; sentinel-folded mask
                    #pragma unroll
                    for (int r = 0; r < 4; ++r) {
                        float s = acc[rf][nf][r];
                        bool m = (idj[nf] != idi[rf][r])
                               & (idj[nf] != idn_s[rf][r])
                               & (seqj[nf] != seq_s[rf][r]);
                        den_acc[rf][r] += m ? __expf(s) : 0.f;
                    }
                }
            }

        // write next tile into the other buffer (reads of it finished at
        // the previous barrier), then one barrier per jt
        if (jt + 1 < NJT) {
            #pragma unroll
            for (int it = 0; it < 4; ++it) {
                int byte = (sq * 16 + it * 64) ^ ((srow & 7) << 4);
                *(bf16x8*)&z2s[cbuf ^ 1][srow * 256 + byte] = stg[it];
            }
        }
        __syncthreads();
        cbuf ^= 1;
    }

    // 16-lane column reduce; single writer per (chunk,row)
    #pragma unroll
    for (int rf = 0; rf < 2; ++rf)
        #pragma unroll
        for (int r = 0; r < 4; ++r) {
            float p = pos_acc[rf][r], dsum = den_acc[rf][r];
            #pragma unroll
            for (int m = 8; m; m >>= 1) {
                p    += __shfl_xor(p, m);
                dsum += __shfl_xor(dsum, m);
            }
            if (c16 == 0) {
                pos_part[chunk * N_TOT + irow[rf][r]] = p;
                den_part[chunk * N_TOT + irow[rf][r]] = dsum;
            }
        }
}

// ---------------- combine per-chunk partials -> scalar loss ----------------
__global__ __launch_bounds__(1024) void loss_finish_kernel(
    const float* __restrict__ pos_part, const float* __restrict__ den_part,
    float* __restrict__ out)
{
    const int t = threadIdx.x;
    float v = 0.f;
    for (int k = 0; k < N_TOT / 1024; ++k) {
        int row = t + k * 1024;
        float pos = 0.f, den = 0.f;
        #pragma unroll
        for (int q = 0; q < NCHUNK; ++q) {
            pos += pos_part[q * N_TOT + row];
            den += den_part[q * N_TOT + row];
        }
        bool two = ((row & (SEQ_L - 1)) != (SEQ_L - 1));
        float npos = two ? 2.f : 1.f;
        v += -(pos - logf(den)) / npos;
    }
    #pragma unroll
    for (int m = 32; m; m >>= 1) v += __shfl_xor(v, m);
    __shared__ float red[16];
    if ((t & 63) == 0) red[t >> 6] = v;
    __syncthreads();
    if (t == 0) {
        float tot = 0.f;
        #pragma unroll
        for (int i = 0; i < 16; ++i) tot += red[i];
        out[0] = tot / (float)N_TOT;
    }
}

extern "C" void kernel_launch(void* const* d_in, const int* in_sizes, int n_in,
                              void* d_out, int out_size, void* d_ws, size_t ws_size,
                              hipStream_t stream)
{
    const int*   ids   = (const int*)d_in[0];
    const float* x1    = (const float*)d_in[2];
    const float* x2    = (const float*)d_in[3];
    const float* w1    = (const float*)d_in[4];
    const float* b1    = (const float*)d_in[5];
    const float* w2    = (const float*)d_in[6];
    const float* b2    = (const float*)d_in[7];
    const float* gamma = (const float*)d_in[8];
    const float* beta  = (const float*)d_in[9];

    char* ws = (char*)d_ws;
    unsigned short* z1b = (unsigned short*)ws;                        // 2MB
    unsigned short* z2b = (unsigned short*)(ws + (2u << 20));         // 2MB
    float* part_s  = (float*)(ws + (4u << 20));                       // 64KB
    float* part_ss = part_s + 2 * 64 * D;                             // 64KB
    float* mu      = part_ss + 2 * 64 * D;
    float* sc      = mu + 2 * D;
    float* pos_part = sc + 2 * D;                                     // 512KB
    float* den_part = pos_part + NCHUNK * N_TOT;                      // 512KB
    unsigned short* w1b = (unsigned short*)(den_part + NCHUNK * N_TOT); // 64KB
    unsigned short* w2b = w1b + 256 * D;                              // 64KB

    convert_w_kernel<<<64, 256, 0, stream>>>(w1, w2, w1b, w2b);
    mlp_mfma_kernel<<<1024, 256, 0, stream>>>(x1, x2, w1b, b1, w2b, b2, z1b, z2b);
    bn_partial_kernel<<<128, 256, 0, stream>>>(z1b, z2b, part_s, part_ss);
    bn_reduce_kernel<<<1, 256, 0, stream>>>(part_s, part_ss, gamma, mu, sc);
    bn_l2_kernel<<<4096, 256, 0, stream>>>(z1b, z2b, mu, sc, beta);
    loss_mfma_kernel<<<1024, 256, 0, stream>>>((const short*)z1b, (const short*)z2b,
                                               ids, pos_part, den_part);
    loss_finish_kernel<<<1, 1024, 0, stream>>>(pos_part, den_part, (float*)d_out);
}

// Round 9
// 89.446 us; speedup vs baseline: 10.7264x; 1.0910x over previous
//
#include <hip/hip_runtime.h>

#define N_TOT 8192
#define SEQ_L 512
#define D 128
#define NCHUNK 16
#define CHUNK (N_TOT / NCHUNK)   // 512 cols per j-chunk == one seq block
#define NJT (CHUNK / 64)         // 8 64-col tiles per chunk
#define LOG2E 1.4426950408889634f
#define LN2   0.6931471805599453f

using bf16x8  = __attribute__((ext_vector_type(8))) short;
using f32x4   = __attribute__((ext_vector_type(4))) float;

static __device__ __forceinline__ unsigned short f2bf(float f) {
    unsigned int u = __float_as_uint(f);
    u = (u + 0x7FFFu + ((u >> 16) & 1u)) >> 16;
    return (unsigned short)u;
}
static __device__ __forceinline__ float bf2f(unsigned short h) {
    return __uint_as_float(((unsigned int)h) << 16);
}
static __device__ __forceinline__ float dot8(bf16x8 a, bf16x8 b) {
    float s = 0.f;
    #pragma unroll
    for (int k = 0; k < 8; ++k)
        s = fmaf(bf2f((unsigned short)a[k]), bf2f((unsigned short)b[k]), s);
    return s;
}

// ---------------- one-shot: convert w1/w2 to bf16 ----------------
__global__ __launch_bounds__(256) void convert_w_kernel(
    const float* __restrict__ w1, const float* __restrict__ w2,
    unsigned short* __restrict__ w1b, unsigned short* __restrict__ w2b)
{
    int idx = blockIdx.x * 256 + threadIdx.x;        // 16384 float4s total
    const float* src = (idx < 8192) ? w1 : w2;
    unsigned short* dst = (idx < 8192) ? w1b : w2b;
    int off = ((idx < 8192) ? idx : idx - 8192) * 4;
    float4 v = *(const float4*)(src + off);
    ushort4 o;
    o.x = f2bf(v.x); o.y = f2bf(v.y); o.z = f2bf(v.z); o.w = f2bf(v.w);
    *(ushort4*)(dst + off) = o;
}

// ---------------- MFMA MLP (32 rows/block) + fused BN column partials ----------------
// grid 512: tensor = bid>>8, r0 = (bid&255)*32. 4 waves: wave w owns
// layer-1 cols w*64..+64, layer-2 cols w*32..+32. Fragment pattern identical
// to the refcheck-verified loss kernel (A row=c16, k=ks*32+g*8; C col=c16,
// row=g*4+r).
__global__ __launch_bounds__(256) void mlp_mfma_kernel(
    const float* __restrict__ x1, const float* __restrict__ x2,
    const unsigned short* __restrict__ w1b, const float* __restrict__ b1,
    const unsigned short* __restrict__ w2b, const float* __restrict__ b2,
    unsigned short* __restrict__ z1, unsigned short* __restrict__ z2,
    float* __restrict__ part_s, float* __restrict__ part_ss)
{
    __shared__ unsigned short hsh[32][264];
    const int t = threadIdx.x;
    const int w = t >> 6;
    const int lane = t & 63;
    const int g = lane >> 4;
    const int c16 = lane & 15;
    const int tensor = blockIdx.x >> 8;
    const int blk = blockIdx.x & 255;
    const int r0 = blk * 32;
    const float* __restrict__ x = tensor ? x2 : x1;
    unsigned short* __restrict__ z = tensor ? z2 : z1;

    // ---- layer 1 ----
    bf16x8 af[2][4];
    #pragma unroll
    for (int rf = 0; rf < 2; ++rf)
        #pragma unroll
        for (int ks = 0; ks < 4; ++ks) {
            const float* xp = x + (size_t)(r0 + rf * 16 + c16) * D + ks * 32 + g * 8;
            float4 u0 = *(const float4*)xp;
            float4 u1 = *(const float4*)(xp + 4);
            bf16x8 a;
            a[0] = f2bf(u0.x); a[1] = f2bf(u0.y); a[2] = f2bf(u0.z); a[3] = f2bf(u0.w);
            a[4] = f2bf(u1.x); a[5] = f2bf(u1.y); a[6] = f2bf(u1.z); a[7] = f2bf(u1.w);
            af[rf][ks] = a;
        }
    f32x4 acc1[2][4] = {};
    #pragma unroll
    for (int ks = 0; ks < 4; ++ks)
        #pragma unroll
        for (int nf = 0; nf < 4; ++nf) {
            int n = w * 64 + nf * 16 + c16;
            bf16x8 b = *(const bf16x8*)(w1b + (size_t)n * D + ks * 32 + g * 8);
            #pragma unroll
            for (int rf = 0; rf < 2; ++rf)
                acc1[rf][nf] = __builtin_amdgcn_mfma_f32_16x16x32_bf16(af[rf][ks], b, acc1[rf][nf], 0, 0, 0);
        }
    #pragma unroll
    for (int nf = 0; nf < 4; ++nf) {
        float bb = b1[w * 64 + nf * 16 + c16];
        #pragma unroll
        for (int rf = 0; rf < 2; ++rf)
            #pragma unroll
            for (int r = 0; r < 4; ++r)
                hsh[rf * 16 + g * 4 + r][w * 64 + nf * 16 + c16] = f2bf(fmaxf(acc1[rf][nf][r] + bb, 0.f));
    }
    __syncthreads();

    // ---- layer 2 ----
    f32x4 acc2[2][2] = {};
    #pragma unroll
    for (int ks = 0; ks < 8; ++ks) {
        bf16x8 a0 = *(const bf16x8*)(&hsh[c16][ks * 32 + g * 8]);
        bf16x8 a1 = *(const bf16x8*)(&hsh[16 + c16][ks * 32 + g * 8]);
        #pragma unroll
        for (int nf = 0; nf < 2; ++nf) {
            int n = w * 32 + nf * 16 + c16;
            bf16x8 b = *(const bf16x8*)(w2b + (size_t)n * 256 + ks * 32 + g * 8);
            acc2[0][nf] = __builtin_amdgcn_mfma_f32_16x16x32_bf16(a0, b, acc2[0][nf], 0, 0, 0);
            acc2[1][nf] = __builtin_amdgcn_mfma_f32_16x16x32_bf16(a1, b, acc2[1][nf], 0, 0, 0);
        }
    }

    // ---- store z + fused BN partials (sum over the block's 32 rows) ----
    #pragma unroll
    for (int nf = 0; nf < 2; ++nf) {
        int col = w * 32 + nf * 16 + c16;
        float bb = b2[col];
        float s = 0.f, ss = 0.f;
        #pragma unroll
        for (int rf = 0; rf < 2; ++rf)
            #pragma unroll
            for (int r = 0; r < 4; ++r) {
                float v = acc2[rf][nf][r] + bb;
                z[(size_t)(r0 + rf * 16 + g * 4 + r) * D + col] = f2bf(v);
                s += v; ss += v * v;
            }
        s  += __shfl_xor(s, 16);  s  += __shfl_xor(s, 32);
        ss += __shfl_xor(ss, 16); ss += __shfl_xor(ss, 32);
        if (g == 0) {
            part_s [((size_t)tensor * 256 + blk) * D + col] = s;
            part_ss[((size_t)tensor * 256 + blk) * D + col] = ss;
        }
    }
}

// ---------------- BN reduce: block per (tensor,col), 256 slabs ----------------
__global__ __launch_bounds__(256) void bn_reduce_kernel(
    const float* __restrict__ part_s, const float* __restrict__ part_ss,
    const float* __restrict__ gamma,
    float* __restrict__ mu, float* __restrict__ sc)
{
    const int t = threadIdx.x;
    const int tensor = blockIdx.x >> 7;
    const int col = blockIdx.x & 127;
    float s  = part_s [((size_t)tensor * 256 + t) * D + col];
    float ss = part_ss[((size_t)tensor * 256 + t) * D + col];
    #pragma unroll
    for (int m = 32; m; m >>= 1) { s += __shfl_xor(s, m); ss += __shfl_xor(ss, m); }
    __shared__ float rs[4], rss[4];
    if ((t & 63) == 0) { rs[t >> 6] = s; rss[t >> 6] = ss; }
    __syncthreads();
    if (t == 0) {
        float S = rs[0] + rs[1] + rs[2] + rs[3];
        float SS = rss[0] + rss[1] + rss[2] + rss[3];
        float m = S / (float)N_TOT;
        float var = SS / (float)N_TOT - m * m;
        mu[tensor * D + col] = m;
        sc[tensor * D + col] = gamma[col] * rsqrtf(var + 1e-5f);
    }
}

// ---------------- BN apply + L2 normalize; z1 additionally scaled by log2e ----------------
__global__ __launch_bounds__(256) void bn_l2_kernel(
    unsigned short* __restrict__ z1, unsigned short* __restrict__ z2,
    const float* __restrict__ mu, const float* __restrict__ sc,
    const float* __restrict__ beta)
{
    const int t = threadIdx.x;
    const int tensor = blockIdx.x >> 11;
    const int row = (blockIdx.x & 2047) * 4 + (t >> 6);
    const int lane = t & 63;
    unsigned short* __restrict__ yr = (tensor ? z2 : z1) + (size_t)row * D;
    const float* __restrict__ mub = mu + tensor * D;
    const float* __restrict__ scb = sc + tensor * D;

    ushort2 v = ((const ushort2*)yr)[lane];
    float2 m2 = ((const float2*)mub)[lane];
    float2 s2 = ((const float2*)scb)[lane];
    float2 b2 = ((const float2*)beta)[lane];
    float v0 = (bf2f(v.x) - m2.x) * s2.x + b2.x;
    float v1 = (bf2f(v.y) - m2.y) * s2.y + b2.y;
    float ssq = v0 * v0 + v1 * v1;
    #pragma unroll
    for (int m = 32; m; m >>= 1) ssq += __shfl_xor(ssq, m);
    float rn = rsqrtf(ssq);
    if (tensor == 0) rn *= LOG2E;   // pre-scale z1 so loss exp = exp2
    ushort2 o; o.x = f2bf(v0 * rn); o.y = f2bf(v1 * rn);
    ((ushort2*)yr)[lane] = o;
}

// ---------------- diagonal-chunk work: pos terms + diag-chunk denominators ----------------
// blocks 0..255: 32 rows each; per row s1=z1s[i].z2[i], s2=z1s[i].z2[i+1]
//   (z1s is log2e-scaled; true s = s_scaled*ln2). two-rows: dden = 2^s1+2^s2.
// blocks 256..271: the 16 rows with i%512==511: full 512-col masked sum over
//   their seq chunk (mask = idj!=idi or j==i).
__global__ __launch_bounds__(256) void diag_kernel(
    const short* __restrict__ z1, const short* __restrict__ z2,
    const int* __restrict__ ids,
    float* __restrict__ posv, float* __restrict__ dden)
{
    const int t = threadIdx.x;
    if (blockIdx.x < 256) {
        const int row = blockIdx.x * 32 + (t >> 3);
        const int le = t & 7;
        const short* ap = z1 + (size_t)row * D + le * 16;
        const short* bp = z2 + (size_t)row * D + le * 16;
        const short* cp = z2 + (size_t)((row + 1) & (N_TOT - 1)) * D + le * 16;
        bf16x8 a0 = *(const bf16x8*)ap, a1 = *(const bf16x8*)(ap + 8);
        float s1 = dot8(a0, *(const bf16x8*)bp) + dot8(a1, *(const bf16x8*)(bp + 8));
        float s2 = dot8(a0, *(const bf16x8*)cp) + dot8(a1, *(const bf16x8*)(cp + 8));
        #pragma unroll
        for (int m = 1; m < 8; m <<= 1) { s1 += __shfl_xor(s1, m); s2 += __shfl_xor(s2, m); }
        if (le == 0) {
            bool two = (row & (SEQ_L - 1)) != (SEQ_L - 1);
            if (two) {
                posv[row] = (s1 + s2) * LN2;
                dden[row] = exp2f(s1) + exp2f(s2);
            } else {
                posv[row] = s1 * LN2;
            }
        }
    } else {
        const int sr = blockIdx.x - 256;
        const int i = sr * SEQ_L + (SEQ_L - 1);
        const int jbase = sr * SEQ_L;
        const int idi_ = ids[i];
        float acc = 0.f;
        #pragma unroll
        for (int c = 0; c < 2; ++c) {
            int j = jbase + t * 2 + c;
            float s = 0.f;
            for (int k = 0; k < 16; ++k) {
                bf16x8 va = *(const bf16x8*)(z1 + (size_t)i * D + k * 8);
                bf16x8 vb = *(const bf16x8*)(z2 + (size_t)j * D + k * 8);
                s += dot8(va, vb);
            }
            bool m = (ids[j] != idi_) | (j == i);
            acc += m ? exp2f(s) : 0.f;
        }
        #pragma unroll
        for (int m = 32; m; m >>= 1) acc += __shfl_xor(acc, m);
        __shared__ float red[4];
        if ((t & 63) == 0) red[t >> 6] = acc;
        __syncthreads();
        if (t == 0) dden[i] = red[0] + red[1] + red[2] + red[3];
    }
}

// ---------------- MFMA S-tile + masked-exp denominators, OFF-DIAGONAL chunks only ----------------
// grid: 15 chunks x 64 row-blocks = 960 (chunk-major -> row-blocks of a chunk
// round-robin over XCDs, z2 chunk L2-hot). Per block: 128 rows x 512 cols.
// Wave w owns rows rb + w*32 exclusively. Epilogue per element: 2 cmp + and +
// sel + exp2 + add (no seq/eq/pos — impossible off-diagonal).
__global__ __launch_bounds__(256) void loss_mfma_kernel(
    const short* __restrict__ z1, const short* __restrict__ z2,
    const int* __restrict__ ids,
    float* __restrict__ den_part)
{
    const int t    = threadIdx.x;
    const int w    = t >> 6;
    const int lane = t & 63;
    const int g    = lane >> 4;
    const int c16  = lane & 15;

    const int c15 = blockIdx.x >> 6;          // 0..14
    const int rbi = blockIdx.x & 63;
    const int rb  = rbi * 128;
    const int seqb = rbi >> 2;                // rows' seq block
    const int chunk = c15 + (c15 >= seqb);    // skip the diagonal chunk
    const int jbase = chunk * CHUNK;

    const int i_wb = rb + w * 32;

    __shared__ __align__(16) unsigned char z2s[2][64 * 256];  // 2 x 16KB

    const int srow = t >> 2;
    const int sq   = t & 3;

    // A fragments (verified pattern)
    bf16x8 af[2][4];
    #pragma unroll
    for (int rf = 0; rf < 2; ++rf)
        #pragma unroll
        for (int ks = 0; ks < 4; ++ks)
            af[rf][ks] = *(const bf16x8*)(z1 + (size_t)(i_wb + rf * 16 + c16) * D + ks * 32 + g * 8);

    // row metadata: idi + sentinel-folded idn
    int idi[2][4], idn_s[2][4];
    #pragma unroll
    for (int rf = 0; rf < 2; ++rf)
        #pragma unroll
        for (int r = 0; r < 4; ++r) {
            int i = i_wb + rf * 16 + g * 4 + r;
            idi[rf][r] = ids[i];
            bool tw = ((i & (SEQ_L - 1)) != (SEQ_L - 1));
            idn_s[rf][r] = tw ? ids[(i + 1) & (N_TOT - 1)] : idi[rf][r];
        }

    // prologue: stage tile 0 + its ids
    #pragma unroll
    for (int it = 0; it < 4; ++it) {
        bf16x8 v = *(const bf16x8*)(z2 + (size_t)(jbase + srow) * D + sq * 8 + it * 32);
        int byte = (sq * 16 + it * 64) ^ ((srow & 7) << 4);
        *(bf16x8*)&z2s[0][srow * 256 + byte] = v;
    }
    int idj[4];
    #pragma unroll
    for (int nf = 0; nf < 4; ++nf) idj[nf] = ids[jbase + nf * 16 + c16];
    __syncthreads();

    float den_acc[2][4] = {};
    int cbuf = 0;

    #pragma unroll 1
    for (int jt = 0; jt < NJT; ++jt) {
        const int cb = jbase + jt * 64;

        // issue next tile's global loads early (T14 split)
        bf16x8 stg[4];
        int idjn[4];
        if (jt + 1 < NJT) {
            #pragma unroll
            for (int it = 0; it < 4; ++it)
                stg[it] = *(const bf16x8*)(z2 + (size_t)(cb + 64 + srow) * D + sq * 8 + it * 32);
            #pragma unroll
            for (int nf = 0; nf < 4; ++nf) idjn[nf] = ids[cb + 64 + nf * 16 + c16];
        }

        f32x4 acc[2][4] = {};
        #pragma unroll
        for (int ks = 0; ks < 4; ++ks)
            #pragma unroll
            for (int nf = 0; nf < 4; ++nf) {
                int r = nf * 16 + c16;
                int byte = (ks * 64 + g * 16) ^ ((r & 7) << 4);
                bf16x8 b = *(const bf16x8*)&z2s[cbuf][r * 256 + byte];
                acc[0][nf] = __builtin_amdgcn_mfma_f32_16x16x32_bf16(af[0][ks], b, acc[0][nf], 0, 0, 0);
                acc[1][nf] = __builtin_amdgcn_mfma_f32_16x16x32_bf16(af[1][ks], b, acc[1][nf], 0, 0, 0);
            }

        // slim epilogue: z1 pre-scaled by log2e -> exp(s) = exp2(acc)
        #pragma unroll
        for (int rf = 0; rf < 2; ++rf)
            #pragma unroll
            for (int nf = 0; nf < 4; ++nf)
                #pragma unroll
                for (int r = 0; r < 4; ++r) {
                    float e = exp2f(acc[rf][nf][r]);
                    bool m = (idj[nf] != idi[rf][r]) & (idj[nf] != idn_s[rf][r]);
                    den_acc[rf][r] += m ? e : 0.f;
                }

        if (jt + 1 < NJT) {
            #pragma unroll
            for (int it = 0; it < 4; ++it) {
                int byte = (sq * 16 + it * 64) ^ ((srow & 7) << 4);
                *(bf16x8*)&z2s[cbuf ^ 1][srow * 256 + byte] = stg[it];
            }
            #pragma unroll
            for (int nf = 0; nf < 4; ++nf) idj[nf] = idjn[nf];
        }
        __syncthreads();
        cbuf ^= 1;
    }

    // 16-lane column reduce; single writer per (chunk,row)
    #pragma unroll
    for (int rf = 0; rf < 2; ++rf)
        #pragma unroll
        for (int r = 0; r < 4; ++r) {
            float dsum = den_acc[rf][r];
            #pragma unroll
            for (int m = 8; m; m >>= 1) dsum += __shfl_xor(dsum, m);
            if (c16 == 0)
                den_part[chunk * N_TOT + i_wb + rf * 16 + g * 4 + r] = dsum;
        }
}

// ---------------- combine: den = dden + off-diag chunks; loss scalar ----------------
__global__ __launch_bounds__(1024) void loss_finish_kernel(
    const float* __restrict__ den_part, const float* __restrict__ posv,
    const float* __restrict__ dden, float* __restrict__ out)
{
    const int t = threadIdx.x;
    float v = 0.f;
    for (int k = 0; k < N_TOT / 1024; ++k) {
        int row = t + k * 1024;
        int seqb = row >> 9;
        float den = dden[row];
        #pragma unroll
        for (int q = 0; q < NCHUNK; ++q)
            if (q != seqb) den += den_part[q * N_TOT + row];
        bool two = ((row & (SEQ_L - 1)) != (SEQ_L - 1));
        float npos = two ? 2.f : 1.f;
        v += -(posv[row] - logf(den)) / npos;
    }
    #pragma unroll
    for (int m = 32; m; m >>= 1) v += __shfl_xor(v, m);
    __shared__ float red[16];
    if ((t & 63) == 0) red[t >> 6] = v;
    __syncthreads();
    if (t == 0) {
        float tot = 0.f;
        #pragma unroll
        for (int i = 0; i < 16; ++i) tot += red[i];
        out[0] = tot / (float)N_TOT;
    }
}

extern "C" void kernel_launch(void* const* d_in, const int* in_sizes, int n_in,
                              void* d_out, int out_size, void* d_ws, size_t ws_size,
                              hipStream_t stream)
{
    const int*   ids   = (const int*)d_in[0];
    const float* x1    = (const float*)d_in[2];
    const float* x2    = (const float*)d_in[3];
    const float* w1    = (const float*)d_in[4];
    const float* b1    = (const float*)d_in[5];
    const float* w2    = (const float*)d_in[6];
    const float* b2    = (const float*)d_in[7];
    const float* gamma = (const float*)d_in[8];
    const float* beta  = (const float*)d_in[9];

    char* ws = (char*)d_ws;
    unsigned short* z1b = (unsigned short*)ws;                          // 2MB
    unsigned short* z2b = (unsigned short*)(ws + (2u << 20));           // 2MB
    float* part_s  = (float*)(ws + (4u << 20));                         // 2*256*128 = 256KB
    float* part_ss = part_s + 2 * 256 * D;                              // 256KB
    float* mu      = part_ss + 2 * 256 * D;
    float* sc      = mu + 2 * D;
    float* den_part = sc + 2 * D;                                       // 16*N = 512KB
    float* posv    = den_part + NCHUNK * N_TOT;                         // 32KB
    float* dden    = posv + N_TOT;                                      // 32KB
    unsigned short* w1b = (unsigned short*)(dden + N_TOT);              // 64KB
    unsigned short* w2b = w1b + 256 * D;                                // 64KB

    convert_w_kernel<<<64, 256, 0, stream>>>(w1, w2, w1b, w2b);
    mlp_mfma_kernel<<<512, 256, 0, stream>>>(x1, x2, w1b, b1, w2b, b2,
                                             z1b, z2b, part_s, part_ss);
    bn_reduce_kernel<<<256, 256, 0, stream>>>(part_s, part_ss, gamma, mu, sc);
    bn_l2_kernel<<<4096, 256, 0, stream>>>(z1b, z2b, mu, sc, beta);
    diag_kernel<<<272, 256, 0, stream>>>((const short*)z1b, (const short*)z2b,
                                         ids, posv, dden);
    loss_mfma_kernel<<<960, 256, 0, stream>>>((const short*)z1b, (const short*)z2b,
                                              ids, den_part);
    loss_finish_kernel<<<1, 1024, 0, stream>>>(den_part, posv, dden, (float*)d_out);
}